// Round 14
// baseline (464.481 us; speedup 1.0000x reference)
//
#include <hip/hip_runtime.h>

// Problem constants (from reference)
constexpr int KDIM  = 128;
constexpr int NEXER = 16384;
constexpr int NNODE = KDIM + NEXER;   // 16512
constexpr int NEDGE = 400000;
constexpr int NBATCH = 4096;
constexpr int NHIST = NBATCH * 50;    // 204800

// CSR build partitioning
constexpr int NCHUNK = 32;
constexpr int CHSZ   = NEDGE / NCHUNK;  // 12500
constexpr int RHALF  = NNODE / 2;       // 8256 -> 33 KB LDS hist

typedef __attribute__((ext_vector_type(8))) short bf16x8;
typedef __attribute__((ext_vector_type(4))) float f32x4;

__device__ __forceinline__ float sigmoidf(float x) {
    return 1.0f / (1.0f + __expf(-x));
}

// round-to-nearest-even fp32 -> bf16 (as ushort)
__device__ __forceinline__ ushort f2bf(float f) {
    uint x = __float_as_uint(f);
    uint r = (x + 0x7FFFu + ((x >> 16) & 1u)) >> 16;
    return (ushort)r;
}

__device__ __forceinline__ void accum8(float* ax, uint4 p, int wbits) {
    float w = __int_as_float(wbits);
    ax[0] += w * __uint_as_float(p.x << 16);
    ax[1] += w * __uint_as_float(p.x & 0xFFFF0000u);
    ax[2] += w * __uint_as_float(p.y << 16);
    ax[3] += w * __uint_as_float(p.y & 0xFFFF0000u);
    ax[4] += w * __uint_as_float(p.z << 16);
    ax[5] += w * __uint_as_float(p.z & 0xFFFF0000u);
    ax[6] += w * __uint_as_float(p.w << 16);
    ax[7] += w * __uint_as_float(p.w & 0xFFFF0000u);
}

__device__ __forceinline__ void accum4(float* ax, uint2 p) {
    ax[0] += __uint_as_float(p.x << 16);
    ax[1] += __uint_as_float(p.x & 0xFFFF0000u);
    ax[2] += __uint_as_float(p.y << 16);
    ax[3] += __uint_as_float(p.y & 0xFFFF0000u);
}

// ---------------------------------------------------------------- fused prep: entity->bf16/full_acc ; gcnW -> Wt ; head weights
constexpr int EMB_BLOCKS = (NNODE * KDIM / 2) / 256;            // 4128
constexpr int W_BLOCKS   = 16 * 12;                             // 192
constexpr int HEAD_ELEMS = 512 * 128 + 224 * 512;               // 180224
constexpr int HEAD_BLOCKS = (HEAD_ELEMS + 255) / 256;           // 704
__global__ __launch_bounds__(256) void prep_all_kernel(
    const float* __restrict__ entity, ushort* __restrict__ h_bf,
    float* __restrict__ full_acc,
    const float* __restrict__ W, ushort* __restrict__ Wt,
    const float* __restrict__ W1, const float* __restrict__ W2,
    ushort* __restrict__ W1t, ushort* __restrict__ W2t)
{
    __shared__ float tile[32][33];
    int bx = blockIdx.x;
    if (bx < EMB_BLOCKS) {
        int idx = bx * 256 + threadIdx.x;
        float2 v = ((const float2*)entity)[idx];
        ((float2*)full_acc)[idx] = v;
        ((uint*)h_bf)[idx] = (uint)f2bf(v.x) | ((uint)f2bf(v.y) << 16);
        return;
    }
    bx -= EMB_BLOCKS;
    if (bx < W_BLOCKS) {
        int gl = bx >> 4;                  // 0..11
        int tl = bx & 15;
        int tk = tl >> 2, tn = tl & 3;
        int k0 = tk * 32, n0 = tn * 32;
        int tx = threadIdx.x & 31, ty = threadIdx.x >> 5;  // ty 0..7
        const float* src = W + ((size_t)gl << 14);
        #pragma unroll
        for (int i = 0; i < 4; ++i) {
            int k = ty * 4 + i;
            tile[k][tx] = src[(k0 + k) * 128 + n0 + tx];
        }
        __syncthreads();
        ushort* dst = Wt + ((size_t)gl << 14);
        #pragma unroll
        for (int i = 0; i < 4; ++i) {
            int n = ty * 4 + i;
            dst[(n0 + n) * 128 + k0 + tx] = f2bf(tile[tx][n]);
        }
        return;
    }
    bx -= W_BLOCKS;
    int idx = bx * 256 + threadIdx.x;
    if (idx < 512 * 128) {
        int n = idx >> 7, k = idx & 127;
        W1t[idx] = f2bf(W1[k * 512 + n]);
    }
    int idx2 = idx - 512 * 128;
    if (idx2 >= 0 && idx2 < 224 * 512) {
        int n = idx2 >> 9, k = idx2 & 511;
        W2t[idx2] = f2bf(n < 216 ? W2[k * 216 + n] : 0.f);
    }
}

// ---------------------------------------------------------------- partial degree hist + per-edge rank (dense writes)
// grid: (NCHUNK, 2, 6)  z = g*2+side (side 0=src,1=dst)
__global__ __launch_bounds__(256) void count_part_kernel(
    const int* __restrict__ s0, const int* __restrict__ d0,
    const int* __restrict__ s1, const int* __restrict__ d1,
    const int* __restrict__ s2, const int* __restrict__ d2,
    int* __restrict__ partial,   // [6][NCHUNK][NNODE]
    ushort* __restrict__ rank)   // [3][NEDGE] (dst side only)
{
    __shared__ int hist[RHALF];
    int c = blockIdx.x, r = blockIdx.y, gs = blockIdx.z;
    const int* arr = (gs == 0) ? s0 : (gs == 1) ? d0 : (gs == 2) ? s1
                   : (gs == 3) ? d1 : (gs == 4) ? s2 : d2;
    for (int i = threadIdx.x; i < RHALF; i += 256) hist[i] = 0;
    __syncthreads();
    int base = r * RHALF;
    const int* p = arr + c * CHSZ;
    if (gs & 1) {
        ushort* rk = rank + (size_t)(gs >> 1) * NEDGE + c * CHSZ;
        for (int i = threadIdx.x; i < CHSZ; i += 256) {
            int v = p[i] - base;
            if ((unsigned)v < (unsigned)RHALF)
                rk[i] = (ushort)atomicAdd(&hist[v], 1);
        }
    } else {
        for (int i = threadIdx.x; i < CHSZ; i += 256) {
            int v = p[i] - base;
            if ((unsigned)v < (unsigned)RHALF) atomicAdd(&hist[v], 1);
        }
    }
    __syncthreads();
    int* outp = partial + ((size_t)gs * NCHUNK + c) * NNODE + base;
    for (int i = threadIdx.x; i < RHALF; i += 256) outp[i] = hist[i];
}

// ---------------------------------------------------------------- sum partials -> cnt[6][NNODE] (degrees, for norm)
__global__ __launch_bounds__(256) void sum_kernel(
    const int* __restrict__ partial, int* __restrict__ cnt)
{
    int idx = blockIdx.x * 256 + threadIdx.x;
    if (idx >= 6 * NNODE) return;
    int gs = idx / NNODE, node = idx - gs * NNODE;
    const int* pp = partial + (size_t)gs * NCHUNK * NNODE + node;
    int s = 0;
    #pragma unroll 8
    for (int c = 0; c < NCHUNK; ++c) s += pp[c * NNODE];
    cnt[idx] = s;
}

// ---------------------------------------------------------------- row_ptr scan (reads cnt dst-planes)
__global__ __launch_bounds__(256) void scan_kernel(
    const int* __restrict__ cnt, int* __restrict__ rp)
{
    int g = blockIdx.x;
    const int* c = cnt + (g * 2 + 1) * NNODE;   // dst side
    int* r = rp + g * (NNODE + 1);
    __shared__ int part[256];
    int t = threadIdx.x;
    constexpr int CH = (NNODE + 255) / 256;  // 65
    int lo = t * CH;
    int hi = lo + CH; if (hi > NNODE) hi = NNODE;
    int s = 0;
    for (int i = lo; i < hi; ++i) s += c[i];
    part[t] = s;
    __syncthreads();
    for (int off = 1; off < 256; off <<= 1) {
        int v = part[t];
        if (t >= off) v += part[t - off];
        __syncthreads();
        part[t] = v;
        __syncthreads();
    }
    int run = (t == 0) ? 0 : part[t - 1];
    for (int i = lo; i < hi; ++i) { r[i] = run; run += c[i]; }
    if (t == 255) r[NNODE] = part[255];
}

// ---------------------------------------------------------------- chunk_base[g][c][node] = rp[node] + excl-scan of dst partials over c
__global__ __launch_bounds__(256) void base_kernel(
    const int* __restrict__ partial, const int* __restrict__ rp,
    int* __restrict__ chunk_base)
{
    int idx = blockIdx.x * 256 + threadIdx.x;
    if (idx >= 3 * NNODE) return;
    int g = idx / NNODE, node = idx - g * NNODE;
    int running = rp[g * (NNODE + 1) + node];
    const int* pp = partial + (size_t)(g * 2 + 1) * NCHUNK * NNODE + node;
    int* ob = chunk_base + (size_t)g * NCHUNK * NNODE + node;
    #pragma unroll 8
    for (int c = 0; c < NCHUNK; ++c) { ob[c * NNODE] = running; running += pp[c * NNODE]; }
}

// ---------------------------------------------------------------- CSR fill: pure parallel scatter (1 thread / edge)
// grid: (ceil(NEDGE/256), 3)
__global__ __launch_bounds__(256) void fill_scatter_kernel(
    const int* __restrict__ s0, const int* __restrict__ d0,
    const int* __restrict__ s1, const int* __restrict__ d1,
    const int* __restrict__ s2, const int* __restrict__ d2,
    const int* __restrict__ cnt, const int* __restrict__ chunk_base,
    const ushort* __restrict__ rank, int2* __restrict__ csr_packed)
{
    int e = blockIdx.x * 256 + threadIdx.x;
    int g = blockIdx.y;
    if (e >= NEDGE) return;
    const int* s = (g == 0) ? s0 : (g == 1) ? s1 : s2;
    const int* d = (g == 0) ? d0 : (g == 1) ? d1 : d2;
    int sv = s[e], dv = d[e];
    int c = e / CHSZ;
    int pos = chunk_base[((size_t)g * NCHUNK + c) * NNODE + dv]
            + (int)rank[(size_t)g * NEDGE + e];
    int a = cnt[(g * 2 + 0) * NNODE + sv]; if (a < 1) a = 1;
    int b = cnt[(g * 2 + 1) * NNODE + dv]; if (b < 1) b = 1;
    float w = rsqrtf((float)a * (float)b);
    csr_packed[(size_t)g * NEDGE + pos] = make_int2(sv, __float_as_int(w));
}

// ---------------------------------------------------------------- CSR gather (bf16 h), 3-stage pipeline (plain loads):
// grid (NNODE/16, 3): wave = 4 rows, 16 lanes/row, lane owns one uint4 (8 cols).
// Pipeline: descs batch k+2 || rows batch k+1 || accumulate batch k.
__global__ __launch_bounds__(256) void gather_kernel(
    const ushort* __restrict__ h_bf, const int2* __restrict__ csr_packed,
    const int* __restrict__ rp, ushort* __restrict__ agg)
{
    int t = threadIdx.x;
    int wave = t >> 6, lane = t & 63;
    int sub = lane >> 4, li = lane & 15;
    int g = blockIdx.y;
    int row = blockIdx.x * 16 + wave * 4 + sub;
    int js = rp[g * (NNODE + 1) + row];
    int je = rp[g * (NNODE + 1) + row + 1];
    const int2* ep = csr_packed + (size_t)g * NEDGE;
    const uint4* hb4 = (const uint4*)h_bf;    // one row = 16 uint4
    float ax[8];
    #pragma unroll
    for (int i = 0; i < 8; ++i) ax[i] = 0.f;
    int j = js;
    if (je - js >= 8) {
        int2 a0 = ep[j], a1 = ep[j + 1], a2 = ep[j + 2], a3 = ep[j + 3];
        int2 b0 = ep[j + 4], b1 = ep[j + 5], b2 = ep[j + 6], b3 = ep[j + 7];
        uint4 ra0 = hb4[(size_t)a0.x * 16 + li];
        uint4 ra1 = hb4[(size_t)a1.x * 16 + li];
        uint4 ra2 = hb4[(size_t)a2.x * 16 + li];
        uint4 ra3 = hb4[(size_t)a3.x * 16 + li];
        j += 8;
        while (j + 3 < je) {
            int2 c0 = ep[j], c1 = ep[j + 1], c2 = ep[j + 2], c3 = ep[j + 3];
            uint4 rb0 = hb4[(size_t)b0.x * 16 + li];
            uint4 rb1 = hb4[(size_t)b1.x * 16 + li];
            uint4 rb2 = hb4[(size_t)b2.x * 16 + li];
            uint4 rb3 = hb4[(size_t)b3.x * 16 + li];
            accum8(ax, ra0, a0.y); accum8(ax, ra1, a1.y);
            accum8(ax, ra2, a2.y); accum8(ax, ra3, a3.y);
            a0 = b0; a1 = b1; a2 = b2; a3 = b3;
            b0 = c0; b1 = c1; b2 = c2; b3 = c3;
            ra0 = rb0; ra1 = rb1; ra2 = rb2; ra3 = rb3;
            j += 4;
        }
        // drain: A has rows; B needs rows
        uint4 rb0 = hb4[(size_t)b0.x * 16 + li];
        uint4 rb1 = hb4[(size_t)b1.x * 16 + li];
        uint4 rb2 = hb4[(size_t)b2.x * 16 + li];
        uint4 rb3 = hb4[(size_t)b3.x * 16 + li];
        accum8(ax, ra0, a0.y); accum8(ax, ra1, a1.y);
        accum8(ax, ra2, a2.y); accum8(ax, ra3, a3.y);
        accum8(ax, rb0, b0.y); accum8(ax, rb1, b1.y);
        accum8(ax, rb2, b2.y); accum8(ax, rb3, b3.y);
    }
    for (; j < je; ++j) {
        int2 e0 = ep[j];
        uint4 p0 = hb4[(size_t)e0.x * 16 + li];
        accum8(ax, p0, e0.y);
    }
    uint4 o;
    o.x = (uint)f2bf(ax[0]) | ((uint)f2bf(ax[1]) << 16);
    o.y = (uint)f2bf(ax[2]) | ((uint)f2bf(ax[3]) << 16);
    o.z = (uint)f2bf(ax[4]) | ((uint)f2bf(ax[5]) << 16);
    o.w = (uint)f2bf(ax[6]) | ((uint)f2bf(ax[7]) << 16);
    ((uint4*)agg)[((size_t)g * NNODE + row) * 16 + li] = o;
}

// ---------------------------------------------------------------- MFMA GEMM: h_next = sum_g agg_g @ W[g,l] + bsum
// layer 2: disc_acc = v ; layer 3: disc_bf = bf16((disc_acc+v)*0.5)
__global__ __launch_bounds__(256) void gemm_kernel(
    const ushort* __restrict__ agg, const ushort* __restrict__ Wt,
    const float* __restrict__ gcnB, int layer,
    ushort* __restrict__ h_bf, float* __restrict__ full_acc,
    float* __restrict__ disc_acc, ushort* __restrict__ disc_bf)
{
    __shared__ ushort Wlds[128 * 136];   // pad 136: 2-way max bank aliasing (free)
    __shared__ float bsum[128];
    int t = threadIdx.x;
    int wave = t >> 6, lane = t & 63;
    int R0 = blockIdx.x * 64;
    if (t < 128)
        bsum[t] = gcnB[(0 * 4 + layer) * 128 + t] + gcnB[(1 * 4 + layer) * 128 + t]
                + gcnB[(2 * 4 + layer) * 128 + t];
    int m = lane & 15, q = lane >> 4;
    int arow = R0 + wave * 16 + m;
    f32x4 acc[8];
    #pragma unroll
    for (int n = 0; n < 8; ++n) acc[n] = (f32x4){0.f, 0.f, 0.f, 0.f};
    for (int g = 0; g < 3; ++g) {
        __syncthreads();
        const ushort* src = Wt + ((size_t)(g * 4 + layer) << 14);
        for (int i = t; i < 2048; i += 256) {          // 128 rows x 16 uint4
            int row = i >> 4, c = i & 15;
            *(uint4*)&Wlds[row * 136 + c * 8] = *(const uint4*)(src + row * 128 + c * 8);
        }
        __syncthreads();
        const ushort* ap = agg + ((size_t)g * NNODE + arow) * 128 + q * 8;
        bf16x8 af[4];
        #pragma unroll
        for (int k = 0; k < 4; ++k) af[k] = *(const bf16x8*)(ap + k * 32);
        #pragma unroll
        for (int n = 0; n < 8; ++n) {
            const ushort* bp = &Wlds[(n * 16 + m) * 136 + q * 8];
            #pragma unroll
            for (int k = 0; k < 4; ++k) {
                bf16x8 bfr = *(const bf16x8*)(bp + k * 32);
                acc[n] = __builtin_amdgcn_mfma_f32_16x16x32_bf16(af[k], bfr, acc[n], 0, 0, 0);
            }
        }
    }
    __syncthreads();
    float* stage = (float*)Wlds;       // reuse LDS (34816 B >= 32768 B)
    #pragma unroll
    for (int n = 0; n < 8; ++n) {
        #pragma unroll
        for (int r = 0; r < 4; ++r)
            stage[(wave * 16 + q * 4 + r) * 128 + n * 16 + m] = acc[n][r];
    }
    __syncthreads();
    for (int idx = t; idx < 64 * 128; idx += 256) {
        int row = idx >> 7, col = idx & 127;
        int gr = R0 + row;
        float v = stage[idx] + bsum[col];
        size_t o = (size_t)gr * 128 + col;
        full_acc[o] += v;
        h_bf[o] = f2bf(v);
        if (gr >= KDIM) {
            size_t od = (size_t)(gr - KDIM) * 128 + col;
            if (layer == 2) disc_acc[od] = v;
            else if (layer == 3) disc_bf[od] = f2bf((disc_acc[od] + v) * 0.5f);
        }
    }
}

// ---------------------------------------------------------------- fused pool + head: 8 batch rows per block (grid 512 -> 2 blocks/CU)
// Stage A: cw (per-block, LDS) + history pooling -> sd (wave = 2 rows x 32 lanes)
// Stage B: x build (rows 8-15 zeroed) ; C/D: MFMA layers ; E: final dot (rr<8 stored).
__global__ __launch_bounds__(256) void pool_head_kernel(
    const ushort* __restrict__ disc_bf, const int* __restrict__ hist,
    const int* __restrict__ segids,
    const float* __restrict__ full,
    const float* __restrict__ fsW, const float* __restrict__ fsB,
    const float* __restrict__ feW, const float* __restrict__ feB,
    const float* __restrict__ disc_emb, const int* __restrict__ exer_id,
    const float* __restrict__ kn,
    const ushort* __restrict__ W1t, const float* __restrict__ b1,
    const ushort* __restrict__ W2t, const float* __restrict__ b2,
    const float* __restrict__ W3, const float* __restrict__ b3,
    float* __restrict__ out)
{
    __shared__ ushort xsl[16][136];   // x bf16, A-layout readable (rows 8-15 zero)
    __shared__ ushort o1l[16][520];   // o1 bf16
    __shared__ float  o2l[16][228];   // o2 f32
    __shared__ float  cwl[256];       // concept @ W[K:], scaled 0.2
    __shared__ float  sdl[8];         // pooled-stu dot fsW[:K]
    int t = threadIdx.x, wave = t >> 6, lane = t & 63;
    int b0 = blockIdx.x * 8;
    float fsb = fsB[0], feb = feB[0];
    // ---- stage A1: cw (redundant per block; 128-len dot per thread)
    {
        int j = t & 127;
        const float* w = (t < 128) ? (fsW + KDIM) : (feW + KDIM);
        const float* row = full + (size_t)j * KDIM;
        float s = 0.f;
        for (int k = 0; k < KDIM; ++k) s += row[k] * w[k];
        cwl[t] = s * 0.2f;   // fold full/5
    }
    // ---- stage A2: history pooling -> sd (wave = 2 rows, 32 lanes/row, lane owns uint2 = 4 bf16)
    {
        int sub = lane >> 5, li = lane & 31;
        int rr = wave * 2 + sub;        // 0..7
        int b = b0 + rr;
        auto bsearch = [&](int key) {
            int lo = 0, hi = NHIST;
            while (lo < hi) {
                int m = (lo + hi) >> 1;
                if (segids[m] < key) lo = m + 1; else hi = m;
            }
            return lo;
        };
        int js = bsearch(b), je = bsearch(b + 1);
        const uint2* db2 = (const uint2*)disc_bf;   // one row = 32 uint2
        float ax[4];
        #pragma unroll
        for (int i = 0; i < 4; ++i) ax[i] = 0.f;
        int j = js;
        if (je - js >= 8) {
            int a0 = hist[j], a1 = hist[j + 1], a2 = hist[j + 2], a3 = hist[j + 3];
            int b0i = hist[j + 4], b1i = hist[j + 5], b2i = hist[j + 6], b3i = hist[j + 7];
            uint2 ra0 = db2[(size_t)a0 * 32 + li];
            uint2 ra1 = db2[(size_t)a1 * 32 + li];
            uint2 ra2 = db2[(size_t)a2 * 32 + li];
            uint2 ra3 = db2[(size_t)a3 * 32 + li];
            j += 8;
            while (j + 3 < je) {
                int c0 = hist[j], c1 = hist[j + 1], c2 = hist[j + 2], c3 = hist[j + 3];
                uint2 rb0 = db2[(size_t)b0i * 32 + li];
                uint2 rb1 = db2[(size_t)b1i * 32 + li];
                uint2 rb2 = db2[(size_t)b2i * 32 + li];
                uint2 rb3 = db2[(size_t)b3i * 32 + li];
                accum4(ax, ra0); accum4(ax, ra1);
                accum4(ax, ra2); accum4(ax, ra3);
                b0i = c0; b1i = c1; b2i = c2; b3i = c3;
                ra0 = rb0; ra1 = rb1; ra2 = rb2; ra3 = rb3;
                j += 4;
            }
            uint2 rb0 = db2[(size_t)b0i * 32 + li];
            uint2 rb1 = db2[(size_t)b1i * 32 + li];
            uint2 rb2 = db2[(size_t)b2i * 32 + li];
            uint2 rb3 = db2[(size_t)b3i * 32 + li];
            accum4(ax, ra0); accum4(ax, ra1);
            accum4(ax, ra2); accum4(ax, ra3);
            accum4(ax, rb0); accum4(ax, rb1);
            accum4(ax, rb2); accum4(ax, rb3);
        }
        for (; j < je; ++j) {
            uint2 p = db2[(size_t)hist[j] * 32 + li];
            accum4(ax, p);
        }
        float c = (float)(je - js); if (c < 1.f) c = 1.f;
        float inv = 1.f / c;
        float sd = 0.f;
        #pragma unroll
        for (int k = 0; k < 4; ++k) sd += ax[k] * inv * fsW[li * 4 + k];
        #pragma unroll
        for (int o = 16; o > 0; o >>= 1) sd += __shfl_xor(sd, o, 32);
        if (li == 0) sdl[rr] = sd;
    }
    __syncthreads();
    // ---- stage B: build x rows (bf16); zero rows 8-15 for the MFMA tile
    #pragma unroll
    for (int i = 0; i < 2; ++i) {
        int rr = wave * 2 + i;          // 0..7
        int b = b0 + rr;
        int eid = exer_id[b];
        const float* er = full + (size_t)(KDIM + eid) * KDIM;
        float ed = er[lane] * feW[lane] + er[lane + 64] * feW[lane + 64];
        #pragma unroll
        for (int o = 32; o > 0; o >>= 1) ed += __shfl_xor(ed, o);
        ed *= 0.2f;   // fold full/5
        float sd = sdl[rr];
        float edisc = 10.f * sigmoidf(disc_emb[eid]);
        for (int j = lane; j < KDIM; j += 64) {
            float prof = sigmoidf(sd + cwl[j] + fsb);
            float diff = sigmoidf(ed + cwl[KDIM + j] + feb);
            xsl[rr][j] = f2bf(edisc * (prof - diff) * kn[(size_t)b * KDIM + j]);
            xsl[8 + rr][j] = 0;
        }
    }
    __syncthreads();
    int m = lane & 15, q = lane >> 4;
    // ---- layer 1 MFMA: wave handles n in [wave*128, wave*128+128)
    bf16x8 af[4];
    #pragma unroll
    for (int kk = 0; kk < 4; ++kk) af[kk] = *(const bf16x8*)&xsl[m][kk * 32 + q * 8];
    f32x4 acc[8];
    #pragma unroll
    for (int n = 0; n < 8; ++n) acc[n] = (f32x4){0.f, 0.f, 0.f, 0.f};
    const ushort* w1base = W1t + (size_t)(wave * 128) * 128;
    #pragma unroll
    for (int nt = 0; nt < 8; ++nt) {
        const ushort* bp = w1base + (nt * 16 + m) * 128 + q * 8;
        #pragma unroll
        for (int kk = 0; kk < 4; ++kk) {
            bf16x8 bf = *(const bf16x8*)(bp + kk * 32);
            acc[nt] = __builtin_amdgcn_mfma_f32_16x16x32_bf16(af[kk], bf, acc[nt], 0, 0, 0);
        }
    }
    #pragma unroll
    for (int nt = 0; nt < 8; ++nt) {
        int n = wave * 128 + nt * 16 + m;
        float bv = b1[n];
        #pragma unroll
        for (int r = 0; r < 4; ++r)
            o1l[q * 4 + r][n] = f2bf(sigmoidf(acc[nt][r] + bv));
    }
    __syncthreads();
    // ---- layer 2 MFMA: 14 n-tiles distributed: wave w takes nt = w, w+4, w+8, (w+12)
    int ntt = (wave < 2) ? 4 : 3;
    f32x4 acc2[4];
    #pragma unroll
    for (int i = 0; i < 4; ++i) acc2[i] = (f32x4){0.f, 0.f, 0.f, 0.f};
    #pragma unroll 4
    for (int kk = 0; kk < 16; ++kk) {
        bf16x8 a2 = *(const bf16x8*)&o1l[m][kk * 32 + q * 8];
        #pragma unroll
        for (int tt = 0; tt < 4; ++tt) {
            if (tt < ntt) {
                int nt = wave + 4 * tt;
                bf16x8 bf = *(const bf16x8*)(W2t + (size_t)(nt * 16 + m) * 512 + kk * 32 + q * 8);
                acc2[tt] = __builtin_amdgcn_mfma_f32_16x16x32_bf16(a2, bf, acc2[tt], 0, 0, 0);
            }
        }
    }
    #pragma unroll
    for (int tt = 0; tt < 4; ++tt) {
        if (tt < ntt) {
            int nt = wave + 4 * tt;
            int n = nt * 16 + m;
            if (n < 216) {
                float bv = b2[n];
                #pragma unroll
                for (int r = 0; r < 4; ++r)
                    o2l[q * 4 + r][n] = sigmoidf(acc2[tt][r] + bv);
            }
        }
    }
    __syncthreads();
    // ---- layer 3: 16-lane dot per row (store only valid rows 0..7)
    int sub = lane >> 4, li = lane & 15;
    int rr = wave * 4 + sub;
    if (rr < 8) {
        float dot = 0.f;
        for (int p = li; p < 216; p += 16) dot += o2l[rr][p] * W3[p];
        #pragma unroll
        for (int o = 8; o > 0; o >>= 1) dot += __shfl_xor(dot, o, 16);
        if (li == 0) out[b0 + rr] = sigmoidf(dot + b3[0]);
    }
}

// ================================================================ host
extern "C" void kernel_launch(void* const* d_in, const int* in_sizes, int n_in,
                              void* d_out, int out_size, void* d_ws, size_t ws_size,
                              hipStream_t stream)
{
    (void)in_sizes; (void)n_in; (void)out_size; (void)ws_size;
    const float* entity = (const float*)d_in[0];
    const float* gcnW   = (const float*)d_in[1];
    const float* gcnB   = (const float*)d_in[2];
    const float* fsW    = (const float*)d_in[3];
    const float* fsB    = (const float*)d_in[4];
    const float* feW    = (const float*)d_in[5];
    const float* feB    = (const float*)d_in[6];
    const float* disc_emb = (const float*)d_in[7];
    const float* W1 = (const float*)d_in[8];
    const float* b1 = (const float*)d_in[9];
    const float* W2 = (const float*)d_in[10];
    const float* b2 = (const float*)d_in[11];
    const float* W3 = (const float*)d_in[12];
    const float* b3 = (const float*)d_in[13];
    const int* s0 = (const int*)d_in[14];
    const int* d0 = (const int*)d_in[15];
    const int* s1 = (const int*)d_in[16];
    const int* d1 = (const int*)d_in[17];
    const int* s2 = (const int*)d_in[18];
    const int* d2 = (const int*)d_in[19];
    const int* exer_id = (const int*)d_in[21];
    const float* kn = (const float*)d_in[22];
    const int* hist = (const int*)d_in[23];
    const int* segid = (const int*)d_in[24];
    float* out = (float*)d_out;

    char* wsb = (char*)d_ws;
    size_t off = 0;
    auto alloc = [&](size_t bytes) -> void* {
        void* p = wsb + off;
        off = (off + bytes + 255) & ~(size_t)255;
        return p;
    };
    int*    partial   = (int*)alloc((size_t)6 * NCHUNK * NNODE * sizeof(int));   // 12.7 MB
    int*    cnt       = (int*)alloc((size_t)6 * NNODE * sizeof(int));
    int*    rp        = (int*)alloc((size_t)3 * (NNODE + 1) * sizeof(int));
    int*    chunk_base= (int*)alloc((size_t)3 * NCHUNK * NNODE * sizeof(int));   // 6.3 MB
    ushort* rank      = (ushort*)alloc((size_t)3 * NEDGE * sizeof(ushort));      // 2.4 MB
    int2*   csr_packed= (int2*)alloc((size_t)3 * NEDGE * sizeof(int2));          // 9.6 MB
    ushort* h_bf      = (ushort*)alloc((size_t)NNODE * KDIM * sizeof(ushort));
    ushort* agg       = (ushort*)alloc((size_t)3 * NNODE * KDIM * sizeof(ushort));
    ushort* Wt        = (ushort*)alloc((size_t)3 * 4 * KDIM * KDIM * sizeof(ushort));
    ushort* W1t       = (ushort*)alloc((size_t)512 * 128 * sizeof(ushort));
    ushort* W2t       = (ushort*)alloc((size_t)224 * 512 * sizeof(ushort));
    float*  full_acc  = (float*)alloc((size_t)NNODE * KDIM * sizeof(float));
    float*  disc_acc  = (float*)alloc((size_t)NEXER * KDIM * sizeof(float));
    ushort* disc_bf   = (ushort*)alloc((size_t)NEXER * KDIM * sizeof(ushort));

    prep_all_kernel<<<EMB_BLOCKS + W_BLOCKS + HEAD_BLOCKS, 256, 0, stream>>>(
        entity, h_bf, full_acc, gcnW, Wt, W1, W2, W1t, W2t);

    // CSR build: LDS-hist counting (ranks recorded), then fully parallel scatter
    count_part_kernel<<<dim3(NCHUNK, 2, 6), 256, 0, stream>>>(s0, d0, s1, d1, s2, d2,
                                                              partial, rank);
    sum_kernel<<<(6 * NNODE + 255) / 256, 256, 0, stream>>>(partial, cnt);
    scan_kernel<<<3, 256, 0, stream>>>(cnt, rp);
    base_kernel<<<(3 * NNODE + 255) / 256, 256, 0, stream>>>(partial, rp, chunk_base);
    fill_scatter_kernel<<<dim3((NEDGE + 255) / 256, 3), 256, 0, stream>>>(
        s0, d0, s1, d1, s2, d2, cnt, chunk_base, rank, csr_packed);

    for (int l = 0; l < 4; ++l) {
        gather_kernel<<<dim3(NNODE / 16, 3), 256, 0, stream>>>(h_bf, csr_packed, rp, agg);
        gemm_kernel<<<NNODE / 64, 256, 0, stream>>>(agg, Wt, gcnB, l, h_bf, full_acc,
                                                    disc_acc, disc_bf);
    }

    pool_head_kernel<<<NBATCH / 8, 256, 0, stream>>>(disc_bf, hist, segid,
                                                     full_acc, fsW, fsB, feW, feB,
                                                     disc_emb, exer_id, kn,
                                                     W1t, b1, W2t, b2, W3, b3, out);
}

// Round 15
// 452.833 us; speedup vs baseline: 1.0257x; 1.0257x over previous
//
#include <hip/hip_runtime.h>

// Problem constants (from reference)
constexpr int KDIM  = 128;
constexpr int NEXER = 16384;
constexpr int NNODE = KDIM + NEXER;   // 16512
constexpr int NEDGE = 400000;
constexpr int NBATCH = 4096;
constexpr int NHIST = NBATCH * 50;    // 204800

// CSR build partitioning
constexpr int NCHUNK = 32;
constexpr int CHSZ   = NEDGE / NCHUNK;  // 12500
constexpr int RHALF  = NNODE / 2;       // 8256 -> 33 KB LDS hist

typedef __attribute__((ext_vector_type(8))) short bf16x8;
typedef __attribute__((ext_vector_type(4))) float f32x4;

__device__ __forceinline__ float sigmoidf(float x) {
    return 1.0f / (1.0f + __expf(-x));
}

// round-to-nearest-even fp32 -> bf16 (as ushort)
__device__ __forceinline__ ushort f2bf(float f) {
    uint x = __float_as_uint(f);
    uint r = (x + 0x7FFFu + ((x >> 16) & 1u)) >> 16;
    return (ushort)r;
}

__device__ __forceinline__ void accum8(float* ax, uint4 p, int wbits) {
    float w = __int_as_float(wbits);
    ax[0] += w * __uint_as_float(p.x << 16);
    ax[1] += w * __uint_as_float(p.x & 0xFFFF0000u);
    ax[2] += w * __uint_as_float(p.y << 16);
    ax[3] += w * __uint_as_float(p.y & 0xFFFF0000u);
    ax[4] += w * __uint_as_float(p.z << 16);
    ax[5] += w * __uint_as_float(p.z & 0xFFFF0000u);
    ax[6] += w * __uint_as_float(p.w << 16);
    ax[7] += w * __uint_as_float(p.w & 0xFFFF0000u);
}

// ---------------------------------------------------------------- fused prep: entity->bf16/full_acc ; gcnW -> Wt ; head weights
constexpr int EMB_BLOCKS = (NNODE * KDIM / 2) / 256;            // 4128
constexpr int W_BLOCKS   = 16 * 12;                             // 192
constexpr int HEAD_ELEMS = 512 * 128 + 224 * 512;               // 180224
constexpr int HEAD_BLOCKS = (HEAD_ELEMS + 255) / 256;           // 704
__global__ __launch_bounds__(256) void prep_all_kernel(
    const float* __restrict__ entity, ushort* __restrict__ h_bf,
    float* __restrict__ full_acc,
    const float* __restrict__ W, ushort* __restrict__ Wt,
    const float* __restrict__ W1, const float* __restrict__ W2,
    ushort* __restrict__ W1t, ushort* __restrict__ W2t)
{
    __shared__ float tile[32][33];
    int bx = blockIdx.x;
    if (bx < EMB_BLOCKS) {
        int idx = bx * 256 + threadIdx.x;
        float2 v = ((const float2*)entity)[idx];
        ((float2*)full_acc)[idx] = v;
        ((uint*)h_bf)[idx] = (uint)f2bf(v.x) | ((uint)f2bf(v.y) << 16);
        return;
    }
    bx -= EMB_BLOCKS;
    if (bx < W_BLOCKS) {
        int gl = bx >> 4;                  // 0..11
        int tl = bx & 15;
        int tk = tl >> 2, tn = tl & 3;
        int k0 = tk * 32, n0 = tn * 32;
        int tx = threadIdx.x & 31, ty = threadIdx.x >> 5;  // ty 0..7
        const float* src = W + ((size_t)gl << 14);
        #pragma unroll
        for (int i = 0; i < 4; ++i) {
            int k = ty * 4 + i;
            tile[k][tx] = src[(k0 + k) * 128 + n0 + tx];
        }
        __syncthreads();
        ushort* dst = Wt + ((size_t)gl << 14);
        #pragma unroll
        for (int i = 0; i < 4; ++i) {
            int n = ty * 4 + i;
            dst[(n0 + n) * 128 + k0 + tx] = f2bf(tile[tx][n]);
        }
        return;
    }
    bx -= W_BLOCKS;
    int idx = bx * 256 + threadIdx.x;
    if (idx < 512 * 128) {
        int n = idx >> 7, k = idx & 127;
        W1t[idx] = f2bf(W1[k * 512 + n]);
    }
    int idx2 = idx - 512 * 128;
    if (idx2 >= 0 && idx2 < 224 * 512) {
        int n = idx2 >> 9, k = idx2 & 511;
        W2t[idx2] = f2bf(n < 216 ? W2[k * 216 + n] : 0.f);
    }
}

// ---------------------------------------------------------------- partial degree hist + per-edge rank (dense writes)
// grid: (NCHUNK, 2, 6)  z = g*2+side (side 0=src,1=dst)
__global__ __launch_bounds__(256) void count_part_kernel(
    const int* __restrict__ s0, const int* __restrict__ d0,
    const int* __restrict__ s1, const int* __restrict__ d1,
    const int* __restrict__ s2, const int* __restrict__ d2,
    int* __restrict__ partial,   // [6][NCHUNK][NNODE]
    ushort* __restrict__ rank)   // [3][NEDGE] (dst side only)
{
    __shared__ int hist[RHALF];
    int c = blockIdx.x, r = blockIdx.y, gs = blockIdx.z;
    const int* arr = (gs == 0) ? s0 : (gs == 1) ? d0 : (gs == 2) ? s1
                   : (gs == 3) ? d1 : (gs == 4) ? s2 : d2;
    for (int i = threadIdx.x; i < RHALF; i += 256) hist[i] = 0;
    __syncthreads();
    int base = r * RHALF;
    const int* p = arr + c * CHSZ;
    if (gs & 1) {
        ushort* rk = rank + (size_t)(gs >> 1) * NEDGE + c * CHSZ;
        for (int i = threadIdx.x; i < CHSZ; i += 256) {
            int v = p[i] - base;
            if ((unsigned)v < (unsigned)RHALF)
                rk[i] = (ushort)atomicAdd(&hist[v], 1);
        }
    } else {
        for (int i = threadIdx.x; i < CHSZ; i += 256) {
            int v = p[i] - base;
            if ((unsigned)v < (unsigned)RHALF) atomicAdd(&hist[v], 1);
        }
    }
    __syncthreads();
    int* outp = partial + ((size_t)gs * NCHUNK + c) * NNODE + base;
    for (int i = threadIdx.x; i < RHALF; i += 256) outp[i] = hist[i];
}

// ---------------------------------------------------------------- sum partials -> cnt[6][NNODE] (degrees, for norm)
__global__ __launch_bounds__(256) void sum_kernel(
    const int* __restrict__ partial, int* __restrict__ cnt)
{
    int idx = blockIdx.x * 256 + threadIdx.x;
    if (idx >= 6 * NNODE) return;
    int gs = idx / NNODE, node = idx - gs * NNODE;
    const int* pp = partial + (size_t)gs * NCHUNK * NNODE + node;
    int s = 0;
    #pragma unroll 8
    for (int c = 0; c < NCHUNK; ++c) s += pp[c * NNODE];
    cnt[idx] = s;
}

// ---------------------------------------------------------------- row_ptr scan (reads cnt dst-planes)
__global__ __launch_bounds__(256) void scan_kernel(
    const int* __restrict__ cnt, int* __restrict__ rp)
{
    int g = blockIdx.x;
    const int* c = cnt + (g * 2 + 1) * NNODE;   // dst side
    int* r = rp + g * (NNODE + 1);
    __shared__ int part[256];
    int t = threadIdx.x;
    constexpr int CH = (NNODE + 255) / 256;  // 65
    int lo = t * CH;
    int hi = lo + CH; if (hi > NNODE) hi = NNODE;
    int s = 0;
    for (int i = lo; i < hi; ++i) s += c[i];
    part[t] = s;
    __syncthreads();
    for (int off = 1; off < 256; off <<= 1) {
        int v = part[t];
        if (t >= off) v += part[t - off];
        __syncthreads();
        part[t] = v;
        __syncthreads();
    }
    int run = (t == 0) ? 0 : part[t - 1];
    for (int i = lo; i < hi; ++i) { r[i] = run; run += c[i]; }
    if (t == 255) r[NNODE] = part[255];
}

// ---------------------------------------------------------------- chunk_base[g][c][node] = rp[node] + excl-scan of dst partials over c
__global__ __launch_bounds__(256) void base_kernel(
    const int* __restrict__ partial, const int* __restrict__ rp,
    int* __restrict__ chunk_base)
{
    int idx = blockIdx.x * 256 + threadIdx.x;
    if (idx >= 3 * NNODE) return;
    int g = idx / NNODE, node = idx - g * NNODE;
    int running = rp[g * (NNODE + 1) + node];
    const int* pp = partial + (size_t)(g * 2 + 1) * NCHUNK * NNODE + node;
    int* ob = chunk_base + (size_t)g * NCHUNK * NNODE + node;
    #pragma unroll 8
    for (int c = 0; c < NCHUNK; ++c) { ob[c * NNODE] = running; running += pp[c * NNODE]; }
}

// ---------------------------------------------------------------- CSR fill: pure parallel scatter (1 thread / edge)
// grid: (ceil(NEDGE/256), 3)
__global__ __launch_bounds__(256) void fill_scatter_kernel(
    const int* __restrict__ s0, const int* __restrict__ d0,
    const int* __restrict__ s1, const int* __restrict__ d1,
    const int* __restrict__ s2, const int* __restrict__ d2,
    const int* __restrict__ cnt, const int* __restrict__ chunk_base,
    const ushort* __restrict__ rank, int2* __restrict__ csr_packed)
{
    int e = blockIdx.x * 256 + threadIdx.x;
    int g = blockIdx.y;
    if (e >= NEDGE) return;
    const int* s = (g == 0) ? s0 : (g == 1) ? s1 : s2;
    const int* d = (g == 0) ? d0 : (g == 1) ? d1 : d2;
    int sv = s[e], dv = d[e];
    int c = e / CHSZ;
    int pos = chunk_base[((size_t)g * NCHUNK + c) * NNODE + dv]
            + (int)rank[(size_t)g * NEDGE + e];
    int a = cnt[(g * 2 + 0) * NNODE + sv]; if (a < 1) a = 1;
    int b = cnt[(g * 2 + 1) * NNODE + dv]; if (b < 1) b = 1;
    float w = rsqrtf((float)a * (float)b);
    csr_packed[(size_t)g * NEDGE + pos] = make_int2(sv, __float_as_int(w));
}

// ---------------------------------------------------------------- CSR gather (bf16 h), 3-stage pipeline (plain loads):
// grid (NNODE/16, 3): wave = 4 rows, 16 lanes/row, lane owns one uint4 (8 cols).
// Pipeline: descs batch k+2 || rows batch k+1 || accumulate batch k.
__global__ __launch_bounds__(256) void gather_kernel(
    const ushort* __restrict__ h_bf, const int2* __restrict__ csr_packed,
    const int* __restrict__ rp, ushort* __restrict__ agg)
{
    int t = threadIdx.x;
    int wave = t >> 6, lane = t & 63;
    int sub = lane >> 4, li = lane & 15;
    int g = blockIdx.y;
    int row = blockIdx.x * 16 + wave * 4 + sub;
    int js = rp[g * (NNODE + 1) + row];
    int je = rp[g * (NNODE + 1) + row + 1];
    const int2* ep = csr_packed + (size_t)g * NEDGE;
    const uint4* hb4 = (const uint4*)h_bf;    // one row = 16 uint4
    float ax[8];
    #pragma unroll
    for (int i = 0; i < 8; ++i) ax[i] = 0.f;
    int j = js;
    if (je - js >= 8) {
        int2 a0 = ep[j], a1 = ep[j + 1], a2 = ep[j + 2], a3 = ep[j + 3];
        int2 b0 = ep[j + 4], b1 = ep[j + 5], b2 = ep[j + 6], b3 = ep[j + 7];
        uint4 ra0 = hb4[(size_t)a0.x * 16 + li];
        uint4 ra1 = hb4[(size_t)a1.x * 16 + li];
        uint4 ra2 = hb4[(size_t)a2.x * 16 + li];
        uint4 ra3 = hb4[(size_t)a3.x * 16 + li];
        j += 8;
        while (j + 3 < je) {
            int2 c0 = ep[j], c1 = ep[j + 1], c2 = ep[j + 2], c3 = ep[j + 3];
            uint4 rb0 = hb4[(size_t)b0.x * 16 + li];
            uint4 rb1 = hb4[(size_t)b1.x * 16 + li];
            uint4 rb2 = hb4[(size_t)b2.x * 16 + li];
            uint4 rb3 = hb4[(size_t)b3.x * 16 + li];
            accum8(ax, ra0, a0.y); accum8(ax, ra1, a1.y);
            accum8(ax, ra2, a2.y); accum8(ax, ra3, a3.y);
            a0 = b0; a1 = b1; a2 = b2; a3 = b3;
            b0 = c0; b1 = c1; b2 = c2; b3 = c3;
            ra0 = rb0; ra1 = rb1; ra2 = rb2; ra3 = rb3;
            j += 4;
        }
        // drain: A has rows; B needs rows
        uint4 rb0 = hb4[(size_t)b0.x * 16 + li];
        uint4 rb1 = hb4[(size_t)b1.x * 16 + li];
        uint4 rb2 = hb4[(size_t)b2.x * 16 + li];
        uint4 rb3 = hb4[(size_t)b3.x * 16 + li];
        accum8(ax, ra0, a0.y); accum8(ax, ra1, a1.y);
        accum8(ax, ra2, a2.y); accum8(ax, ra3, a3.y);
        accum8(ax, rb0, b0.y); accum8(ax, rb1, b1.y);
        accum8(ax, rb2, b2.y); accum8(ax, rb3, b3.y);
    }
    for (; j < je; ++j) {
        int2 e0 = ep[j];
        uint4 p0 = hb4[(size_t)e0.x * 16 + li];
        accum8(ax, p0, e0.y);
    }
    uint4 o;
    o.x = (uint)f2bf(ax[0]) | ((uint)f2bf(ax[1]) << 16);
    o.y = (uint)f2bf(ax[2]) | ((uint)f2bf(ax[3]) << 16);
    o.z = (uint)f2bf(ax[4]) | ((uint)f2bf(ax[5]) << 16);
    o.w = (uint)f2bf(ax[6]) | ((uint)f2bf(ax[7]) << 16);
    ((uint4*)agg)[((size_t)g * NNODE + row) * 16 + li] = o;
}

// ---------------------------------------------------------------- MFMA GEMM: h_next = sum_g agg_g @ W[g,l] + bsum
// layer 2: disc_acc = v ; layer 3: disc_bf = bf16((disc_acc+v)*0.5)
__global__ __launch_bounds__(256) void gemm_kernel(
    const ushort* __restrict__ agg, const ushort* __restrict__ Wt,
    const float* __restrict__ gcnB, int layer,
    ushort* __restrict__ h_bf, float* __restrict__ full_acc,
    float* __restrict__ disc_acc, ushort* __restrict__ disc_bf)
{
    __shared__ ushort Wlds[128 * 136];   // pad 136: 2-way max bank aliasing (free)
    __shared__ float bsum[128];
    int t = threadIdx.x;
    int wave = t >> 6, lane = t & 63;
    int R0 = blockIdx.x * 64;
    if (t < 128)
        bsum[t] = gcnB[(0 * 4 + layer) * 128 + t] + gcnB[(1 * 4 + layer) * 128 + t]
                + gcnB[(2 * 4 + layer) * 128 + t];
    int m = lane & 15, q = lane >> 4;
    int arow = R0 + wave * 16 + m;
    f32x4 acc[8];
    #pragma unroll
    for (int n = 0; n < 8; ++n) acc[n] = (f32x4){0.f, 0.f, 0.f, 0.f};
    for (int g = 0; g < 3; ++g) {
        __syncthreads();
        const ushort* src = Wt + ((size_t)(g * 4 + layer) << 14);
        for (int i = t; i < 2048; i += 256) {          // 128 rows x 16 uint4
            int row = i >> 4, c = i & 15;
            *(uint4*)&Wlds[row * 136 + c * 8] = *(const uint4*)(src + row * 128 + c * 8);
        }
        __syncthreads();
        const ushort* ap = agg + ((size_t)g * NNODE + arow) * 128 + q * 8;
        bf16x8 af[4];
        #pragma unroll
        for (int k = 0; k < 4; ++k) af[k] = *(const bf16x8*)(ap + k * 32);
        #pragma unroll
        for (int n = 0; n < 8; ++n) {
            const ushort* bp = &Wlds[(n * 16 + m) * 136 + q * 8];
            #pragma unroll
            for (int k = 0; k < 4; ++k) {
                bf16x8 bfr = *(const bf16x8*)(bp + k * 32);
                acc[n] = __builtin_amdgcn_mfma_f32_16x16x32_bf16(af[k], bfr, acc[n], 0, 0, 0);
            }
        }
    }
    __syncthreads();
    float* stage = (float*)Wlds;       // reuse LDS (34816 B >= 32768 B)
    #pragma unroll
    for (int n = 0; n < 8; ++n) {
        #pragma unroll
        for (int r = 0; r < 4; ++r)
            stage[(wave * 16 + q * 4 + r) * 128 + n * 16 + m] = acc[n][r];
    }
    __syncthreads();
    for (int idx = t; idx < 64 * 128; idx += 256) {
        int row = idx >> 7, col = idx & 127;
        int gr = R0 + row;
        float v = stage[idx] + bsum[col];
        size_t o = (size_t)gr * 128 + col;
        full_acc[o] += v;
        h_bf[o] = f2bf(v);
        if (gr >= KDIM) {
            size_t od = (size_t)(gr - KDIM) * 128 + col;
            if (layer == 2) disc_acc[od] = v;
            else if (layer == 3) disc_bf[od] = f2bf((disc_acc[od] + v) * 0.5f);
        }
    }
}

// ---------------------------------------------------------------- fused pool + head: 16 batch rows per block
// Stage A: cw (per-block, LDS) + history pooling -> sd (in-register dot, no stu buffer)
// Stage B: x build ; C/D: MFMA layers ; E: final dot.
__global__ __launch_bounds__(256) void pool_head_kernel(
    const ushort* __restrict__ disc_bf, const int* __restrict__ hist,
    const int* __restrict__ segids,
    const float* __restrict__ full,
    const float* __restrict__ fsW, const float* __restrict__ fsB,
    const float* __restrict__ feW, const float* __restrict__ feB,
    const float* __restrict__ disc_emb, const int* __restrict__ exer_id,
    const float* __restrict__ kn,
    const ushort* __restrict__ W1t, const float* __restrict__ b1,
    const ushort* __restrict__ W2t, const float* __restrict__ b2,
    const float* __restrict__ W3, const float* __restrict__ b3,
    float* __restrict__ out)
{
    __shared__ ushort xsl[16][136];   // x bf16, A-layout readable
    __shared__ ushort o1l[16][520];   // o1 bf16
    __shared__ float  o2l[16][228];   // o2 f32
    __shared__ float  cwl[256];       // concept @ W[K:], scaled 0.2
    __shared__ float  sdl[16];        // pooled-stu dot fsW[:K]
    int t = threadIdx.x, wave = t >> 6, lane = t & 63;
    int b0 = blockIdx.x * 16;
    float fsb = fsB[0], feb = feB[0];
    // ---- stage A1: cw (redundant per block; 128-len dot per thread)
    {
        int j = t & 127;
        const float* w = (t < 128) ? (fsW + KDIM) : (feW + KDIM);
        const float* row = full + (size_t)j * KDIM;
        float s = 0.f;
        for (int k = 0; k < KDIM; ++k) s += row[k] * w[k];
        cwl[t] = s * 0.2f;   // fold full/5
    }
    // ---- stage A2: history pooling -> sd (wave = 4 rows, 16 lanes/row)
    {
        int sub = lane >> 4, li = lane & 15;
        int rr = wave * 4 + sub;
        int b = b0 + rr;
        auto bsearch = [&](int key) {
            int lo = 0, hi = NHIST;
            while (lo < hi) {
                int m = (lo + hi) >> 1;
                if (segids[m] < key) lo = m + 1; else hi = m;
            }
            return lo;
        };
        int js = bsearch(b), je = bsearch(b + 1);
        const uint4* db4 = (const uint4*)disc_bf;
        float ax[8];
        #pragma unroll
        for (int i = 0; i < 8; ++i) ax[i] = 0.f;
        int one = __float_as_int(1.0f);
        int j = js;
        if (je - js >= 8) {
            int a0 = hist[j], a1 = hist[j + 1], a2 = hist[j + 2], a3 = hist[j + 3];
            int b0i = hist[j + 4], b1i = hist[j + 5], b2i = hist[j + 6], b3i = hist[j + 7];
            uint4 ra0 = db4[(size_t)a0 * 16 + li];
            uint4 ra1 = db4[(size_t)a1 * 16 + li];
            uint4 ra2 = db4[(size_t)a2 * 16 + li];
            uint4 ra3 = db4[(size_t)a3 * 16 + li];
            j += 8;
            while (j + 3 < je) {
                int c0 = hist[j], c1 = hist[j + 1], c2 = hist[j + 2], c3 = hist[j + 3];
                uint4 rb0 = db4[(size_t)b0i * 16 + li];
                uint4 rb1 = db4[(size_t)b1i * 16 + li];
                uint4 rb2 = db4[(size_t)b2i * 16 + li];
                uint4 rb3 = db4[(size_t)b3i * 16 + li];
                accum8(ax, ra0, one); accum8(ax, ra1, one);
                accum8(ax, ra2, one); accum8(ax, ra3, one);
                b0i = c0; b1i = c1; b2i = c2; b3i = c3;
                ra0 = rb0; ra1 = rb1; ra2 = rb2; ra3 = rb3;
                j += 4;
            }
            uint4 rb0 = db4[(size_t)b0i * 16 + li];
            uint4 rb1 = db4[(size_t)b1i * 16 + li];
            uint4 rb2 = db4[(size_t)b2i * 16 + li];
            uint4 rb3 = db4[(size_t)b3i * 16 + li];
            accum8(ax, ra0, one); accum8(ax, ra1, one);
            accum8(ax, ra2, one); accum8(ax, ra3, one);
            accum8(ax, rb0, one); accum8(ax, rb1, one);
            accum8(ax, rb2, one); accum8(ax, rb3, one);
        }
        for (; j < je; ++j) {
            uint4 p = db4[(size_t)hist[j] * 16 + li];
            accum8(ax, p, one);
        }
        float c = (float)(je - js); if (c < 1.f) c = 1.f;
        float inv = 1.f / c;
        float sd = 0.f;
        #pragma unroll
        for (int k = 0; k < 8; ++k) sd += ax[k] * inv * fsW[li * 8 + k];
        #pragma unroll
        for (int o = 8; o > 0; o >>= 1) sd += __shfl_xor(sd, o, 16);
        if (li == 0) sdl[rr] = sd;
    }
    __syncthreads();
    // ---- stage B: build x rows (bf16)
    #pragma unroll
    for (int i = 0; i < 4; ++i) {
        int rr = wave * 4 + i;
        int b = b0 + rr;
        int eid = exer_id[b];
        const float* er = full + (size_t)(KDIM + eid) * KDIM;
        float ed = er[lane] * feW[lane] + er[lane + 64] * feW[lane + 64];
        #pragma unroll
        for (int o = 32; o > 0; o >>= 1) ed += __shfl_xor(ed, o);
        ed *= 0.2f;   // fold full/5
        float sd = sdl[rr];
        float edisc = 10.f * sigmoidf(disc_emb[eid]);
        for (int j = lane; j < KDIM; j += 64) {
            float prof = sigmoidf(sd + cwl[j] + fsb);
            float diff = sigmoidf(ed + cwl[KDIM + j] + feb);
            xsl[rr][j] = f2bf(edisc * (prof - diff) * kn[(size_t)b * KDIM + j]);
        }
    }
    __syncthreads();
    int m = lane & 15, q = lane >> 4;
    // ---- layer 1 MFMA: wave handles n in [wave*128, wave*128+128)
    bf16x8 af[4];
    #pragma unroll
    for (int kk = 0; kk < 4; ++kk) af[kk] = *(const bf16x8*)&xsl[m][kk * 32 + q * 8];
    f32x4 acc[8];
    #pragma unroll
    for (int n = 0; n < 8; ++n) acc[n] = (f32x4){0.f, 0.f, 0.f, 0.f};
    const ushort* w1base = W1t + (size_t)(wave * 128) * 128;
    #pragma unroll
    for (int nt = 0; nt < 8; ++nt) {
        const ushort* bp = w1base + (nt * 16 + m) * 128 + q * 8;
        #pragma unroll
        for (int kk = 0; kk < 4; ++kk) {
            bf16x8 bf = *(const bf16x8*)(bp + kk * 32);
            acc[nt] = __builtin_amdgcn_mfma_f32_16x16x32_bf16(af[kk], bf, acc[nt], 0, 0, 0);
        }
    }
    #pragma unroll
    for (int nt = 0; nt < 8; ++nt) {
        int n = wave * 128 + nt * 16 + m;
        float bv = b1[n];
        #pragma unroll
        for (int r = 0; r < 4; ++r)
            o1l[q * 4 + r][n] = f2bf(sigmoidf(acc[nt][r] + bv));
    }
    __syncthreads();
    // ---- layer 2 MFMA: 14 n-tiles distributed: wave w takes nt = w, w+4, w+8, (w+12)
    int ntt = (wave < 2) ? 4 : 3;
    f32x4 acc2[4];
    #pragma unroll
    for (int i = 0; i < 4; ++i) acc2[i] = (f32x4){0.f, 0.f, 0.f, 0.f};
    #pragma unroll 4
    for (int kk = 0; kk < 16; ++kk) {
        bf16x8 a2 = *(const bf16x8*)&o1l[m][kk * 32 + q * 8];
        #pragma unroll
        for (int tt = 0; tt < 4; ++tt) {
            if (tt < ntt) {
                int nt = wave + 4 * tt;
                bf16x8 bf = *(const bf16x8*)(W2t + (size_t)(nt * 16 + m) * 512 + kk * 32 + q * 8);
                acc2[tt] = __builtin_amdgcn_mfma_f32_16x16x32_bf16(a2, bf, acc2[tt], 0, 0, 0);
            }
        }
    }
    #pragma unroll
    for (int tt = 0; tt < 4; ++tt) {
        if (tt < ntt) {
            int nt = wave + 4 * tt;
            int n = nt * 16 + m;
            if (n < 216) {
                float bv = b2[n];
                #pragma unroll
                for (int r = 0; r < 4; ++r)
                    o2l[q * 4 + r][n] = sigmoidf(acc2[tt][r] + bv);
            }
        }
    }
    __syncthreads();
    // ---- layer 3: 16-lane dot per row
    int sub = lane >> 4, li = lane & 15;
    int rr = wave * 4 + sub;
    float dot = 0.f;
    for (int p = li; p < 216; p += 16) dot += o2l[rr][p] * W3[p];
    #pragma unroll
    for (int o = 8; o > 0; o >>= 1) dot += __shfl_xor(dot, o, 16);
    if (li == 0) out[b0 + rr] = sigmoidf(dot + b3[0]);
}

// ================================================================ host
extern "C" void kernel_launch(void* const* d_in, const int* in_sizes, int n_in,
                              void* d_out, int out_size, void* d_ws, size_t ws_size,
                              hipStream_t stream)
{
    (void)in_sizes; (void)n_in; (void)out_size; (void)ws_size;
    const float* entity = (const float*)d_in[0];
    const float* gcnW   = (const float*)d_in[1];
    const float* gcnB   = (const float*)d_in[2];
    const float* fsW    = (const float*)d_in[3];
    const float* fsB    = (const float*)d_in[4];
    const float* feW    = (const float*)d_in[5];
    const float* feB    = (const float*)d_in[6];
    const float* disc_emb = (const float*)d_in[7];
    const float* W1 = (const float*)d_in[8];
    const float* b1 = (const float*)d_in[9];
    const float* W2 = (const float*)d_in[10];
    const float* b2 = (const float*)d_in[11];
    const float* W3 = (const float*)d_in[12];
    const float* b3 = (const float*)d_in[13];
    const int* s0 = (const int*)d_in[14];
    const int* d0 = (const int*)d_in[15];
    const int* s1 = (const int*)d_in[16];
    const int* d1 = (const int*)d_in[17];
    const int* s2 = (const int*)d_in[18];
    const int* d2 = (const int*)d_in[19];
    const int* exer_id = (const int*)d_in[21];
    const float* kn = (const float*)d_in[22];
    const int* hist = (const int*)d_in[23];
    const int* segid = (const int*)d_in[24];
    float* out = (float*)d_out;

    char* wsb = (char*)d_ws;
    size_t off = 0;
    auto alloc = [&](size_t bytes) -> void* {
        void* p = wsb + off;
        off = (off + bytes + 255) & ~(size_t)255;
        return p;
    };
    int*    partial   = (int*)alloc((size_t)6 * NCHUNK * NNODE * sizeof(int));   // 12.7 MB
    int*    cnt       = (int*)alloc((size_t)6 * NNODE * sizeof(int));
    int*    rp        = (int*)alloc((size_t)3 * (NNODE + 1) * sizeof(int));
    int*    chunk_base= (int*)alloc((size_t)3 * NCHUNK * NNODE * sizeof(int));   // 6.3 MB
    ushort* rank      = (ushort*)alloc((size_t)3 * NEDGE * sizeof(ushort));      // 2.4 MB
    int2*   csr_packed= (int2*)alloc((size_t)3 * NEDGE * sizeof(int2));          // 9.6 MB
    ushort* h_bf      = (ushort*)alloc((size_t)NNODE * KDIM * sizeof(ushort));
    ushort* agg       = (ushort*)alloc((size_t)3 * NNODE * KDIM * sizeof(ushort));
    ushort* Wt        = (ushort*)alloc((size_t)3 * 4 * KDIM * KDIM * sizeof(ushort));
    ushort* W1t       = (ushort*)alloc((size_t)512 * 128 * sizeof(ushort));
    ushort* W2t       = (ushort*)alloc((size_t)224 * 512 * sizeof(ushort));
    float*  full_acc  = (float*)alloc((size_t)NNODE * KDIM * sizeof(float));
    float*  disc_acc  = (float*)alloc((size_t)NEXER * KDIM * sizeof(float));
    ushort* disc_bf   = (ushort*)alloc((size_t)NEXER * KDIM * sizeof(ushort));

    prep_all_kernel<<<EMB_BLOCKS + W_BLOCKS + HEAD_BLOCKS, 256, 0, stream>>>(
        entity, h_bf, full_acc, gcnW, Wt, W1, W2, W1t, W2t);

    // CSR build: LDS-hist counting (ranks recorded), then fully parallel scatter
    count_part_kernel<<<dim3(NCHUNK, 2, 6), 256, 0, stream>>>(s0, d0, s1, d1, s2, d2,
                                                              partial, rank);
    sum_kernel<<<(6 * NNODE + 255) / 256, 256, 0, stream>>>(partial, cnt);
    scan_kernel<<<3, 256, 0, stream>>>(cnt, rp);
    base_kernel<<<(3 * NNODE + 255) / 256, 256, 0, stream>>>(partial, rp, chunk_base);
    fill_scatter_kernel<<<dim3((NEDGE + 255) / 256, 3), 256, 0, stream>>>(
        s0, d0, s1, d1, s2, d2, cnt, chunk_base, rank, csr_packed);

    for (int l = 0; l < 4; ++l) {
        gather_kernel<<<dim3(NNODE / 16, 3), 256, 0, stream>>>(h_bf, csr_packed, rp, agg);
        gemm_kernel<<<NNODE / 64, 256, 0, stream>>>(agg, Wt, gcnB, l, h_bf, full_acc,
                                                    disc_acc, disc_bf);
    }

    pool_head_kernel<<<NBATCH / 16, 256, 0, stream>>>(disc_bf, hist, segid,
                                                      full_acc, fsW, fsB, feW, feB,
                                                      disc_emb, exer_id, kn,
                                                      W1t, b1, W2t, b2, W3, b3, out);
}

// Round 17
// 416.225 us; speedup vs baseline: 1.1159x; 1.0880x over previous
//
#include <hip/hip_runtime.h>

// Problem constants (from reference)
constexpr int KDIM  = 128;
constexpr int NEXER = 16384;
constexpr int NNODE = KDIM + NEXER;   // 16512
constexpr int NEDGE = 400000;
constexpr int NBATCH = 4096;
constexpr int NHIST = NBATCH * 50;    // 204800

// CSR build partitioning
constexpr int NCHUNK = 32;
constexpr int CHSZ   = NEDGE / NCHUNK;  // 12500
constexpr int RHALF  = NNODE / 2;       // 8256 -> 33 KB LDS hist

// h stored as fp8 e4m3 scaled by HSCALE; 1/HSCALE folded into csr weights.
constexpr float HSCALE = 32.f;
constexpr float HINV   = 1.f / 32.f;

typedef __attribute__((ext_vector_type(8))) short bf16x8;
typedef __attribute__((ext_vector_type(4))) float f32x4;
typedef __attribute__((ext_vector_type(2))) float f32x2;

__device__ __forceinline__ float sigmoidf(float x) {
    return 1.0f / (1.0f + __expf(-x));
}

// round-to-nearest-even fp32 -> bf16 (as ushort)
__device__ __forceinline__ ushort f2bf(float f) {
    uint x = __float_as_uint(f);
    uint r = (x + 0x7FFFu + ((x >> 16) & 1u)) >> 16;
    return (ushort)r;
}

// ---- fp8 e4m3 helpers (HW conversion on gfx950, guarded fallback) ----
#if __has_builtin(__builtin_amdgcn_cvt_pk_fp8_f32) && __has_builtin(__builtin_amdgcn_cvt_pk_f32_fp8)
#define HAVE_HW_FP8 1
#else
#define HAVE_HW_FP8 0
#endif

__device__ __forceinline__ uint fp8_encode1(float f) {
    // manual e4m3fn encode (fallback only)
    uint sign = (__float_as_uint(f) >> 31) << 7;
    float a = fabsf(f);
    if (a >= 448.f) return sign | 0x7E;
    if (a < 0.0009765625f) return sign;           // < half min-subnormal
    if (a >= 0.015625f) {
        int e; float m = frexpf(a, &e);           // a = m*2^e, m in [0.5,1)
        int E = e + 6;
        int q = (int)rintf(m * 16.f);             // [8,16]
        if (q == 16) { q = 8; E += 1; }
        if (E >= 16) return sign | 0x7E;
        return sign | ((uint)E << 3) | (uint)(q - 8);
    } else {
        int q = (int)rintf(a * 512.f);
        if (q > 7) return sign | (1u << 3);
        return sign | (uint)q;
    }
}

__device__ __forceinline__ float fp8_decode1(uint b) {
    uint s = b >> 7, e = (b >> 3) & 15, m = b & 7;
    float v = (e == 0) ? (float)m * 0.001953125f
                       : ldexpf((float)(8 + m), (int)e - 10);
    return s ? -v : v;
}

// encode pair (a,b) into low 16 bits of a uint
__device__ __forceinline__ ushort fp8_pk2(float a, float b) {
#if HAVE_HW_FP8
    return (ushort)(__builtin_amdgcn_cvt_pk_fp8_f32(a, b, 0, false) & 0xFFFF);
#else
    return (ushort)(fp8_encode1(a) | (fp8_encode1(b) << 8));
#endif
}

__device__ __forceinline__ void accum8f8(float* ax, uint2 p, int wbits) {
    float w = __int_as_float(wbits);
#if HAVE_HW_FP8
    f32x2 v0 = __builtin_amdgcn_cvt_pk_f32_fp8(p.x, false);
    f32x2 v1 = __builtin_amdgcn_cvt_pk_f32_fp8(p.x, true);
    f32x2 v2 = __builtin_amdgcn_cvt_pk_f32_fp8(p.y, false);
    f32x2 v3 = __builtin_amdgcn_cvt_pk_f32_fp8(p.y, true);
    ax[0] += w * v0.x; ax[1] += w * v0.y;
    ax[2] += w * v1.x; ax[3] += w * v1.y;
    ax[4] += w * v2.x; ax[5] += w * v2.y;
    ax[6] += w * v3.x; ax[7] += w * v3.y;
#else
    ax[0] += w * fp8_decode1(p.x & 255);        ax[1] += w * fp8_decode1((p.x >> 8) & 255);
    ax[2] += w * fp8_decode1((p.x >> 16) & 255); ax[3] += w * fp8_decode1(p.x >> 24);
    ax[4] += w * fp8_decode1(p.y & 255);        ax[5] += w * fp8_decode1((p.y >> 8) & 255);
    ax[6] += w * fp8_decode1((p.y >> 16) & 255); ax[7] += w * fp8_decode1(p.y >> 24);
#endif
}

__device__ __forceinline__ float hclamp(float v) {
    return fmaxf(fminf(v, 440.f), -440.f);
}

__device__ __forceinline__ void accum8(float* ax, uint4 p, int wbits) {
    float w = __int_as_float(wbits);
    ax[0] += w * __uint_as_float(p.x << 16);
    ax[1] += w * __uint_as_float(p.x & 0xFFFF0000u);
    ax[2] += w * __uint_as_float(p.y << 16);
    ax[3] += w * __uint_as_float(p.y & 0xFFFF0000u);
    ax[4] += w * __uint_as_float(p.z << 16);
    ax[5] += w * __uint_as_float(p.z & 0xFFFF0000u);
    ax[6] += w * __uint_as_float(p.w << 16);
    ax[7] += w * __uint_as_float(p.w & 0xFFFF0000u);
}

// ---------------------------------------------------------------- fused prep: entity->fp8/full_acc ; gcnW -> Wt ; head weights
constexpr int EMB_BLOCKS = (NNODE * KDIM / 2) / 256;            // 4128
constexpr int W_BLOCKS   = 16 * 12;                             // 192
constexpr int HEAD_ELEMS = 512 * 128 + 224 * 512;               // 180224
constexpr int HEAD_BLOCKS = (HEAD_ELEMS + 255) / 256;           // 704
__global__ __launch_bounds__(256) void prep_all_kernel(
    const float* __restrict__ entity, ushort* __restrict__ h8,
    float* __restrict__ full_acc,
    const float* __restrict__ W, ushort* __restrict__ Wt,
    const float* __restrict__ W1, const float* __restrict__ W2,
    ushort* __restrict__ W1t, ushort* __restrict__ W2t)
{
    __shared__ float tile[32][33];
    int bx = blockIdx.x;
    if (bx < EMB_BLOCKS) {
        int idx = bx * 256 + threadIdx.x;
        float2 v = ((const float2*)entity)[idx];
        ((float2*)full_acc)[idx] = v;
        h8[idx] = fp8_pk2(hclamp(v.x * HSCALE), hclamp(v.y * HSCALE));
        return;
    }
    bx -= EMB_BLOCKS;
    if (bx < W_BLOCKS) {
        int gl = bx >> 4;                  // 0..11
        int tl = bx & 15;
        int tk = tl >> 2, tn = tl & 3;
        int k0 = tk * 32, n0 = tn * 32;
        int tx = threadIdx.x & 31, ty = threadIdx.x >> 5;  // ty 0..7
        const float* src = W + ((size_t)gl << 14);
        #pragma unroll
        for (int i = 0; i < 4; ++i) {
            int k = ty * 4 + i;
            tile[k][tx] = src[(k0 + k) * 128 + n0 + tx];
        }
        __syncthreads();
        ushort* dst = Wt + ((size_t)gl << 14);
        #pragma unroll
        for (int i = 0; i < 4; ++i) {
            int n = ty * 4 + i;
            dst[(n0 + n) * 128 + k0 + tx] = f2bf(tile[tx][n]);
        }
        return;
    }
    bx -= W_BLOCKS;
    int idx = bx * 256 + threadIdx.x;
    if (idx < 512 * 128) {
        int n = idx >> 7, k = idx & 127;
        W1t[idx] = f2bf(W1[k * 512 + n]);
    }
    int idx2 = idx - 512 * 128;
    if (idx2 >= 0 && idx2 < 224 * 512) {
        int n = idx2 >> 9, k = idx2 & 511;
        W2t[idx2] = f2bf(n < 216 ? W2[k * 216 + n] : 0.f);
    }
}

// ---------------------------------------------------------------- partial degree hist + per-edge rank (dense writes)
// grid: (NCHUNK, 2, 6)  z = g*2+side (side 0=src,1=dst)
__global__ __launch_bounds__(256) void count_part_kernel(
    const int* __restrict__ s0, const int* __restrict__ d0,
    const int* __restrict__ s1, const int* __restrict__ d1,
    const int* __restrict__ s2, const int* __restrict__ d2,
    int* __restrict__ partial,   // [6][NCHUNK][NNODE]
    ushort* __restrict__ rank)   // [3][NEDGE] (dst side only)
{
    __shared__ int hist[RHALF];
    int c = blockIdx.x, r = blockIdx.y, gs = blockIdx.z;
    const int* arr = (gs == 0) ? s0 : (gs == 1) ? d0 : (gs == 2) ? s1
                   : (gs == 3) ? d1 : (gs == 4) ? s2 : d2;
    for (int i = threadIdx.x; i < RHALF; i += 256) hist[i] = 0;
    __syncthreads();
    int base = r * RHALF;
    const int* p = arr + c * CHSZ;
    if (gs & 1) {
        ushort* rk = rank + (size_t)(gs >> 1) * NEDGE + c * CHSZ;
        for (int i = threadIdx.x; i < CHSZ; i += 256) {
            int v = p[i] - base;
            if ((unsigned)v < (unsigned)RHALF)
                rk[i] = (ushort)atomicAdd(&hist[v], 1);
        }
    } else {
        for (int i = threadIdx.x; i < CHSZ; i += 256) {
            int v = p[i] - base;
            if ((unsigned)v < (unsigned)RHALF) atomicAdd(&hist[v], 1);
        }
    }
    __syncthreads();
    int* outp = partial + ((size_t)gs * NCHUNK + c) * NNODE + base;
    for (int i = threadIdx.x; i < RHALF; i += 256) outp[i] = hist[i];
}

// ---------------------------------------------------------------- sum partials -> cnt[6][NNODE] (degrees, for norm)
__global__ __launch_bounds__(256) void sum_kernel(
    const int* __restrict__ partial, int* __restrict__ cnt)
{
    int idx = blockIdx.x * 256 + threadIdx.x;
    if (idx >= 6 * NNODE) return;
    int gs = idx / NNODE, node = idx - gs * NNODE;
    const int* pp = partial + (size_t)gs * NCHUNK * NNODE + node;
    int s = 0;
    #pragma unroll 8
    for (int c = 0; c < NCHUNK; ++c) s += pp[c * NNODE];
    cnt[idx] = s;
}

// ---------------------------------------------------------------- row_ptr scan (reads cnt dst-planes)
__global__ __launch_bounds__(256) void scan_kernel(
    const int* __restrict__ cnt, int* __restrict__ rp)
{
    int g = blockIdx.x;
    const int* c = cnt + (g * 2 + 1) * NNODE;   // dst side
    int* r = rp + g * (NNODE + 1);
    __shared__ int part[256];
    int t = threadIdx.x;
    constexpr int CH = (NNODE + 255) / 256;  // 65
    int lo = t * CH;
    int hi = lo + CH; if (hi > NNODE) hi = NNODE;
    int s = 0;
    for (int i = lo; i < hi; ++i) s += c[i];
    part[t] = s;
    __syncthreads();
    for (int off = 1; off < 256; off <<= 1) {
        int v = part[t];
        if (t >= off) v += part[t - off];
        __syncthreads();
        part[t] = v;
        __syncthreads();
    }
    int run = (t == 0) ? 0 : part[t - 1];
    for (int i = lo; i < hi; ++i) { r[i] = run; run += c[i]; }
    if (t == 255) r[NNODE] = part[255];
}

// ---------------------------------------------------------------- chunk_base[g][c][node] = rp[node] + excl-scan of dst partials over c
__global__ __launch_bounds__(256) void base_kernel(
    const int* __restrict__ partial, const int* __restrict__ rp,
    int* __restrict__ chunk_base)
{
    int idx = blockIdx.x * 256 + threadIdx.x;
    if (idx >= 3 * NNODE) return;
    int g = idx / NNODE, node = idx - g * NNODE;
    int running = rp[g * (NNODE + 1) + node];
    const int* pp = partial + (size_t)(g * 2 + 1) * NCHUNK * NNODE + node;
    int* ob = chunk_base + (size_t)g * NCHUNK * NNODE + node;
    #pragma unroll 8
    for (int c = 0; c < NCHUNK; ++c) { ob[c * NNODE] = running; running += pp[c * NNODE]; }
}

// ---------------------------------------------------------------- CSR fill: pure parallel scatter (1 thread / edge)
// weight carries the 1/HSCALE factor to undo the fp8 h scaling exactly.
__global__ __launch_bounds__(256) void fill_scatter_kernel(
    const int* __restrict__ s0, const int* __restrict__ d0,
    const int* __restrict__ s1, const int* __restrict__ d1,
    const int* __restrict__ s2, const int* __restrict__ d2,
    const int* __restrict__ cnt, const int* __restrict__ chunk_base,
    const ushort* __restrict__ rank, int2* __restrict__ csr_packed)
{
    int e = blockIdx.x * 256 + threadIdx.x;
    int g = blockIdx.y;
    if (e >= NEDGE) return;
    const int* s = (g == 0) ? s0 : (g == 1) ? s1 : s2;
    const int* d = (g == 0) ? d0 : (g == 1) ? d1 : d2;
    int sv = s[e], dv = d[e];
    int c = e / CHSZ;
    int pos = chunk_base[((size_t)g * NCHUNK + c) * NNODE + dv]
            + (int)rank[(size_t)g * NEDGE + e];
    int a = cnt[(g * 2 + 0) * NNODE + sv]; if (a < 1) a = 1;
    int b = cnt[(g * 2 + 1) * NNODE + dv]; if (b < 1) b = 1;
    float w = rsqrtf((float)a * (float)b) * HINV;
    csr_packed[(size_t)g * NEDGE + pos] = make_int2(sv, __float_as_int(w));
}

// ---------------------------------------------------------------- CSR gather (fp8 h), 3-stage pipeline:
// grid (NNODE/16, 3): wave = 4 rows, 16 lanes/row, lane owns one uint2 (8 fp8 cols).
// Pipeline: descs batch k+2 || rows batch k+1 || accumulate batch k.
__global__ __launch_bounds__(256) void gather_kernel(
    const ushort* __restrict__ h8, const int2* __restrict__ csr_packed,
    const int* __restrict__ rp, ushort* __restrict__ agg)
{
    int t = threadIdx.x;
    int wave = t >> 6, lane = t & 63;
    int sub = lane >> 4, li = lane & 15;
    int g = blockIdx.y;
    int row = blockIdx.x * 16 + wave * 4 + sub;
    int js = rp[g * (NNODE + 1) + row];
    int je = rp[g * (NNODE + 1) + row + 1];
    const int2* ep = csr_packed + (size_t)g * NEDGE;
    const uint2* hb2 = (const uint2*)h8;    // one row = 128 fp8 = 16 uint2
    float ax[8];
    #pragma unroll
    for (int i = 0; i < 8; ++i) ax[i] = 0.f;
    int j = js;
    if (je - js >= 8) {
        int2 a0 = ep[j], a1 = ep[j + 1], a2 = ep[j + 2], a3 = ep[j + 3];
        int2 b0 = ep[j + 4], b1 = ep[j + 5], b2 = ep[j + 6], b3 = ep[j + 7];
        uint2 ra0 = hb2[(size_t)a0.x * 16 + li];
        uint2 ra1 = hb2[(size_t)a1.x * 16 + li];
        uint2 ra2 = hb2[(size_t)a2.x * 16 + li];
        uint2 ra3 = hb2[(size_t)a3.x * 16 + li];
        j += 8;
        while (j + 3 < je) {
            int2 c0 = ep[j], c1 = ep[j + 1], c2 = ep[j + 2], c3 = ep[j + 3];
            uint2 rb0 = hb2[(size_t)b0.x * 16 + li];
            uint2 rb1 = hb2[(size_t)b1.x * 16 + li];
            uint2 rb2 = hb2[(size_t)b2.x * 16 + li];
            uint2 rb3 = hb2[(size_t)b3.x * 16 + li];
            accum8f8(ax, ra0, a0.y); accum8f8(ax, ra1, a1.y);
            accum8f8(ax, ra2, a2.y); accum8f8(ax, ra3, a3.y);
            a0 = b0; a1 = b1; a2 = b2; a3 = b3;
            b0 = c0; b1 = c1; b2 = c2; b3 = c3;
            ra0 = rb0; ra1 = rb1; ra2 = rb2; ra3 = rb3;
            j += 4;
        }
        // drain: A has rows; B needs rows
        uint2 rb0 = hb2[(size_t)b0.x * 16 + li];
        uint2 rb1 = hb2[(size_t)b1.x * 16 + li];
        uint2 rb2 = hb2[(size_t)b2.x * 16 + li];
        uint2 rb3 = hb2[(size_t)b3.x * 16 + li];
        accum8f8(ax, ra0, a0.y); accum8f8(ax, ra1, a1.y);
        accum8f8(ax, ra2, a2.y); accum8f8(ax, ra3, a3.y);
        accum8f8(ax, rb0, b0.y); accum8f8(ax, rb1, b1.y);
        accum8f8(ax, rb2, b2.y); accum8f8(ax, rb3, b3.y);
    }
    for (; j < je; ++j) {
        int2 e0 = ep[j];
        uint2 p0 = hb2[(size_t)e0.x * 16 + li];
        accum8f8(ax, p0, e0.y);
    }
    uint4 o;
    o.x = (uint)f2bf(ax[0]) | ((uint)f2bf(ax[1]) << 16);
    o.y = (uint)f2bf(ax[2]) | ((uint)f2bf(ax[3]) << 16);
    o.z = (uint)f2bf(ax[4]) | ((uint)f2bf(ax[5]) << 16);
    o.w = (uint)f2bf(ax[6]) | ((uint)f2bf(ax[7]) << 16);
    ((uint4*)agg)[((size_t)g * NNODE + row) * 16 + li] = o;
}

// ---------------------------------------------------------------- MFMA GEMM: h_next = sum_g agg_g @ W[g,l] + bsum
// epilogue: h8 = fp8(v*HSCALE) ; layer 2: disc_acc = v ; layer 3: disc_bf = bf16((disc_acc+v)*0.5)
__global__ __launch_bounds__(256) void gemm_kernel(
    const ushort* __restrict__ agg, const ushort* __restrict__ Wt,
    const float* __restrict__ gcnB, int layer,
    ushort* __restrict__ h8, float* __restrict__ full_acc,
    float* __restrict__ disc_acc, ushort* __restrict__ disc_bf)
{
    __shared__ ushort Wlds[128 * 136];   // pad 136: 2-way max bank aliasing (free)
    __shared__ float bsum[128];
    int t = threadIdx.x;
    int wave = t >> 6, lane = t & 63;
    int R0 = blockIdx.x * 64;
    if (t < 128)
        bsum[t] = gcnB[(0 * 4 + layer) * 128 + t] + gcnB[(1 * 4 + layer) * 128 + t]
                + gcnB[(2 * 4 + layer) * 128 + t];
    int m = lane & 15, q = lane >> 4;
    int arow = R0 + wave * 16 + m;
    f32x4 acc[8];
    #pragma unroll
    for (int n = 0; n < 8; ++n) acc[n] = (f32x4){0.f, 0.f, 0.f, 0.f};
    for (int g = 0; g < 3; ++g) {
        __syncthreads();
        const ushort* src = Wt + ((size_t)(g * 4 + layer) << 14);
        for (int i = t; i < 2048; i += 256) {          // 128 rows x 16 uint4
            int row = i >> 4, c = i & 15;
            *(uint4*)&Wlds[row * 136 + c * 8] = *(const uint4*)(src + row * 128 + c * 8);
        }
        __syncthreads();
        const ushort* ap = agg + ((size_t)g * NNODE + arow) * 128 + q * 8;
        bf16x8 af[4];
        #pragma unroll
        for (int k = 0; k < 4; ++k) af[k] = *(const bf16x8*)(ap + k * 32);
        #pragma unroll
        for (int n = 0; n < 8; ++n) {
            const ushort* bp = &Wlds[(n * 16 + m) * 136 + q * 8];
            #pragma unroll
            for (int k = 0; k < 4; ++k) {
                bf16x8 bfr = *(const bf16x8*)(bp + k * 32);
                acc[n] = __builtin_amdgcn_mfma_f32_16x16x32_bf16(af[k], bfr, acc[n], 0, 0, 0);
            }
        }
    }
    __syncthreads();
    float* stage = (float*)Wlds;       // reuse LDS (34816 B >= 32768 B)
    #pragma unroll
    for (int n = 0; n < 8; ++n) {
        #pragma unroll
        for (int r = 0; r < 4; ++r)
            stage[(wave * 16 + q * 4 + r) * 128 + n * 16 + m] = acc[n][r];
    }
    __syncthreads();
    for (int idx = t; idx < 64 * 64; idx += 256) {     // col-pair granularity
        int row = idx >> 6, cp = idx & 63;
        int gr = R0 + row;
        int c0 = cp * 2;
        float v0 = stage[row * 128 + c0] + bsum[c0];
        float v1 = stage[row * 128 + c0 + 1] + bsum[c0 + 1];
        size_t o = (size_t)gr * 128 + c0;
        float2 f = *(float2*)&full_acc[o];
        f.x += v0; f.y += v1;
        *(float2*)&full_acc[o] = f;
        h8[(size_t)gr * 64 + cp] = fp8_pk2(hclamp(v0 * HSCALE), hclamp(v1 * HSCALE));
        if (gr >= KDIM) {
            size_t od = (size_t)(gr - KDIM) * 64 + cp;
            if (layer == 2) {
                *(float2*)&disc_acc[od * 2] = make_float2(v0, v1);
            } else if (layer == 3) {
                float2 dv = *(const float2*)&disc_acc[od * 2];
                ((uint*)disc_bf)[od] = (uint)f2bf((dv.x + v0) * 0.5f)
                                     | ((uint)f2bf((dv.y + v1) * 0.5f) << 16);
            }
        }
    }
}

// ---------------------------------------------------------------- fused pool + head: 16 batch rows per block
__global__ __launch_bounds__(256) void pool_head_kernel(
    const ushort* __restrict__ disc_bf, const int* __restrict__ hist,
    const int* __restrict__ segids,
    const float* __restrict__ full,
    const float* __restrict__ fsW, const float* __restrict__ fsB,
    const float* __restrict__ feW, const float* __restrict__ feB,
    const float* __restrict__ disc_emb, const int* __restrict__ exer_id,
    const float* __restrict__ kn,
    const ushort* __restrict__ W1t, const float* __restrict__ b1,
    const ushort* __restrict__ W2t, const float* __restrict__ b2,
    const float* __restrict__ W3, const float* __restrict__ b3,
    float* __restrict__ out)
{
    __shared__ ushort xsl[16][136];   // x bf16, A-layout readable
    __shared__ ushort o1l[16][520];   // o1 bf16
    __shared__ float  o2l[16][228];   // o2 f32
    __shared__ float  cwl[256];       // concept @ W[K:], scaled 0.2
    __shared__ float  sdl[16];        // pooled-stu dot fsW[:K]
    int t = threadIdx.x, wave = t >> 6, lane = t & 63;
    int b0 = blockIdx.x * 16;
    float fsb = fsB[0], feb = feB[0];
    // ---- stage A1: cw (redundant per block; 128-len dot per thread)
    {
        int j = t & 127;
        const float* w = (t < 128) ? (fsW + KDIM) : (feW + KDIM);
        const float* row = full + (size_t)j * KDIM;
        float s = 0.f;
        for (int k = 0; k < KDIM; ++k) s += row[k] * w[k];
        cwl[t] = s * 0.2f;   // fold full/5
    }
    // ---- stage A2: history pooling -> sd (wave = 4 rows, 16 lanes/row)
    {
        int sub = lane >> 4, li = lane & 15;
        int rr = wave * 4 + sub;
        int b = b0 + rr;
        auto bsearch = [&](int key) {
            int lo = 0, hi = NHIST;
            while (lo < hi) {
                int m = (lo + hi) >> 1;
                if (segids[m] < key) lo = m + 1; else hi = m;
            }
            return lo;
        };
        int js = bsearch(b), je = bsearch(b + 1);
        const uint4* db4 = (const uint4*)disc_bf;
        float ax[8];
        #pragma unroll
        for (int i = 0; i < 8; ++i) ax[i] = 0.f;
        int one = __float_as_int(1.0f);
        int j = js;
        if (je - js >= 8) {
            int a0 = hist[j], a1 = hist[j + 1], a2 = hist[j + 2], a3 = hist[j + 3];
            int b0i = hist[j + 4], b1i = hist[j + 5], b2i = hist[j + 6], b3i = hist[j + 7];
            uint4 ra0 = db4[(size_t)a0 * 16 + li];
            uint4 ra1 = db4[(size_t)a1 * 16 + li];
            uint4 ra2 = db4[(size_t)a2 * 16 + li];
            uint4 ra3 = db4[(size_t)a3 * 16 + li];
            j += 8;
            while (j + 3 < je) {
                int c0 = hist[j], c1 = hist[j + 1], c2 = hist[j + 2], c3 = hist[j + 3];
                uint4 rb0 = db4[(size_t)b0i * 16 + li];
                uint4 rb1 = db4[(size_t)b1i * 16 + li];
                uint4 rb2 = db4[(size_t)b2i * 16 + li];
                uint4 rb3 = db4[(size_t)b3i * 16 + li];
                accum8(ax, ra0, one); accum8(ax, ra1, one);
                accum8(ax, ra2, one); accum8(ax, ra3, one);
                b0i = c0; b1i = c1; b2i = c2; b3i = c3;
                ra0 = rb0; ra1 = rb1; ra2 = rb2; ra3 = rb3;
                j += 4;
            }
            uint4 rb0 = db4[(size_t)b0i * 16 + li];
            uint4 rb1 = db4[(size_t)b1i * 16 + li];
            uint4 rb2 = db4[(size_t)b2i * 16 + li];
            uint4 rb3 = db4[(size_t)b3i * 16 + li];
            accum8(ax, ra0, one); accum8(ax, ra1, one);
            accum8(ax, ra2, one); accum8(ax, ra3, one);
            accum8(ax, rb0, one); accum8(ax, rb1, one);
            accum8(ax, rb2, one); accum8(ax, rb3, one);
        }
        for (; j < je; ++j) {
            uint4 p = db4[(size_t)hist[j] * 16 + li];
            accum8(ax, p, one);
        }
        float c = (float)(je - js); if (c < 1.f) c = 1.f;
        float inv = 1.f / c;
        float sd = 0.f;
        #pragma unroll
        for (int k = 0; k < 8; ++k) sd += ax[k] * inv * fsW[li * 8 + k];
        #pragma unroll
        for (int o = 8; o > 0; o >>= 1) sd += __shfl_xor(sd, o, 16);
        if (li == 0) sdl[rr] = sd;
    }
    __syncthreads();
    // ---- stage B: build x rows (bf16)
    #pragma unroll
    for (int i = 0; i < 4; ++i) {
        int rr = wave * 4 + i;
        int b = b0 + rr;
        int eid = exer_id[b];
        const float* er = full + (size_t)(KDIM + eid) * KDIM;
        float ed = er[lane] * feW[lane] + er[lane + 64] * feW[lane + 64];
        #pragma unroll
        for (int o = 32; o > 0; o >>= 1) ed += __shfl_xor(ed, o);
        ed *= 0.2f;   // fold full/5
        float sd = sdl[rr];
        float edisc = 10.f * sigmoidf(disc_emb[eid]);
        for (int j = lane; j < KDIM; j += 64) {
            float prof = sigmoidf(sd + cwl[j] + fsb);
            float diff = sigmoidf(ed + cwl[KDIM + j] + feb);
            xsl[rr][j] = f2bf(edisc * (prof - diff) * kn[(size_t)b * KDIM + j]);
        }
    }
    __syncthreads();
    int m = lane & 15, q = lane >> 4;
    // ---- layer 1 MFMA: wave handles n in [wave*128, wave*128+128)
    bf16x8 af[4];
    #pragma unroll
    for (int kk = 0; kk < 4; ++kk) af[kk] = *(const bf16x8*)&xsl[m][kk * 32 + q * 8];
    f32x4 acc[8];
    #pragma unroll
    for (int n = 0; n < 8; ++n) acc[n] = (f32x4){0.f, 0.f, 0.f, 0.f};
    const ushort* w1base = W1t + (size_t)(wave * 128) * 128;
    #pragma unroll
    for (int nt = 0; nt < 8; ++nt) {
        const ushort* bp = w1base + (nt * 16 + m) * 128 + q * 8;
        #pragma unroll
        for (int kk = 0; kk < 4; ++kk) {
            bf16x8 bf = *(const bf16x8*)(bp + kk * 32);
            acc[nt] = __builtin_amdgcn_mfma_f32_16x16x32_bf16(af[kk], bf, acc[nt], 0, 0, 0);
        }
    }
    #pragma unroll
    for (int nt = 0; nt < 8; ++nt) {
        int n = wave * 128 + nt * 16 + m;
        float bv = b1[n];
        #pragma unroll
        for (int r = 0; r < 4; ++r)
            o1l[q * 4 + r][n] = f2bf(sigmoidf(acc[nt][r] + bv));
    }
    __syncthreads();
    // ---- layer 2 MFMA: 14 n-tiles distributed: wave w takes nt = w, w+4, w+8, (w+12)
    int ntt = (wave < 2) ? 4 : 3;
    f32x4 acc2[4];
    #pragma unroll
    for (int i = 0; i < 4; ++i) acc2[i] = (f32x4){0.f, 0.f, 0.f, 0.f};
    #pragma unroll 4
    for (int kk = 0; kk < 16; ++kk) {
        bf16x8 a2 = *(const bf16x8*)&o1l[m][kk * 32 + q * 8];
        #pragma unroll
        for (int tt = 0; tt < 4; ++tt) {
            if (tt < ntt) {
                int nt = wave + 4 * tt;
                bf16x8 bf = *(const bf16x8*)(W2t + (size_t)(nt * 16 + m) * 512 + kk * 32 + q * 8);
                acc2[tt] = __builtin_amdgcn_mfma_f32_16x16x32_bf16(a2, bf, acc2[tt], 0, 0, 0);
            }
        }
    }
    #pragma unroll
    for (int tt = 0; tt < 4; ++tt) {
        if (tt < ntt) {
            int nt = wave + 4 * tt;
            int n = nt * 16 + m;
            if (n < 216) {
                float bv = b2[n];
                #pragma unroll
                for (int r = 0; r < 4; ++r)
                    o2l[q * 4 + r][n] = sigmoidf(acc2[tt][r] + bv);
            }
        }
    }
    __syncthreads();
    // ---- layer 3: 16-lane dot per row
    int sub = lane >> 4, li = lane & 15;
    int rr = wave * 4 + sub;
    float dot = 0.f;
    for (int p = li; p < 216; p += 16) dot += o2l[rr][p] * W3[p];
    #pragma unroll
    for (int o = 8; o > 0; o >>= 1) dot += __shfl_xor(dot, o, 16);
    if (li == 0) out[b0 + rr] = sigmoidf(dot + b3[0]);
}

// ================================================================ host
extern "C" void kernel_launch(void* const* d_in, const int* in_sizes, int n_in,
                              void* d_out, int out_size, void* d_ws, size_t ws_size,
                              hipStream_t stream)
{
    (void)in_sizes; (void)n_in; (void)out_size; (void)ws_size;
    const float* entity = (const float*)d_in[0];
    const float* gcnW   = (const float*)d_in[1];
    const float* gcnB   = (const float*)d_in[2];
    const float* fsW    = (const float*)d_in[3];
    const float* fsB    = (const float*)d_in[4];
    const float* feW    = (const float*)d_in[5];
    const float* feB    = (const float*)d_in[6];
    const float* disc_emb = (const float*)d_in[7];
    const float* W1 = (const float*)d_in[8];
    const float* b1 = (const float*)d_in[9];
    const float* W2 = (const float*)d_in[10];
    const float* b2 = (const float*)d_in[11];
    const float* W3 = (const float*)d_in[12];
    const float* b3 = (const float*)d_in[13];
    const int* s0 = (const int*)d_in[14];
    const int* d0 = (const int*)d_in[15];
    const int* s1 = (const int*)d_in[16];
    const int* d1 = (const int*)d_in[17];
    const int* s2 = (const int*)d_in[18];
    const int* d2 = (const int*)d_in[19];
    const int* exer_id = (const int*)d_in[21];
    const float* kn = (const float*)d_in[22];
    const int* hist = (const int*)d_in[23];
    const int* segid = (const int*)d_in[24];
    float* out = (float*)d_out;

    char* wsb = (char*)d_ws;
    size_t off = 0;
    auto alloc = [&](size_t bytes) -> void* {
        void* p = wsb + off;
        off = (off + bytes + 255) & ~(size_t)255;
        return p;
    };
    int*    partial   = (int*)alloc((size_t)6 * NCHUNK * NNODE * sizeof(int));   // 12.7 MB
    int*    cnt       = (int*)alloc((size_t)6 * NNODE * sizeof(int));
    int*    rp        = (int*)alloc((size_t)3 * (NNODE + 1) * sizeof(int));
    int*    chunk_base= (int*)alloc((size_t)3 * NCHUNK * NNODE * sizeof(int));   // 6.3 MB
    ushort* rank      = (ushort*)alloc((size_t)3 * NEDGE * sizeof(ushort));      // 2.4 MB
    int2*   csr_packed= (int2*)alloc((size_t)3 * NEDGE * sizeof(int2));          // 9.6 MB
    ushort* h8        = (ushort*)alloc((size_t)NNODE * KDIM);                    // fp8: 2.1 MB (ushort = 2 fp8)
    ushort* agg       = (ushort*)alloc((size_t)3 * NNODE * KDIM * sizeof(ushort));
    ushort* Wt        = (ushort*)alloc((size_t)3 * 4 * KDIM * KDIM * sizeof(ushort));
    ushort* W1t       = (ushort*)alloc((size_t)512 * 128 * sizeof(ushort));
    ushort* W2t       = (ushort*)alloc((size_t)224 * 512 * sizeof(ushort));
    float*  full_acc  = (float*)alloc((size_t)NNODE * KDIM * sizeof(float));
    float*  disc_acc  = (float*)alloc((size_t)NEXER * KDIM * sizeof(float));
    ushort* disc_bf   = (ushort*)alloc((size_t)NEXER * KDIM * sizeof(ushort));

    prep_all_kernel<<<EMB_BLOCKS + W_BLOCKS + HEAD_BLOCKS, 256, 0, stream>>>(
        entity, h8, full_acc, gcnW, Wt, W1, W2, W1t, W2t);

    // CSR build: LDS-hist counting (ranks recorded), then fully parallel scatter
    count_part_kernel<<<dim3(NCHUNK, 2, 6), 256, 0, stream>>>(s0, d0, s1, d1, s2, d2,
                                                              partial, rank);
    sum_kernel<<<(6 * NNODE + 255) / 256, 256, 0, stream>>>(partial, cnt);
    scan_kernel<<<3, 256, 0, stream>>>(cnt, rp);
    base_kernel<<<(3 * NNODE + 255) / 256, 256, 0, stream>>>(partial, rp, chunk_base);
    fill_scatter_kernel<<<dim3((NEDGE + 255) / 256, 3), 256, 0, stream>>>(
        s0, d0, s1, d1, s2, d2, cnt, chunk_base, rank, csr_packed);

    for (int l = 0; l < 4; ++l) {
        gather_kernel<<<dim3(NNODE / 16, 3), 256, 0, stream>>>(h8, csr_packed, rp, agg);
        gemm_kernel<<<NNODE / 64, 256, 0, stream>>>(agg, Wt, gcnB, l, h8, full_acc,
                                                    disc_acc, disc_bf);
    }

    pool_head_kernel<<<NBATCH / 16, 256, 0, stream>>>(disc_bf, hist, segid,
                                                      full_acc, fsW, fsB, feW, feB,
                                                      disc_emb, exer_id, kn,
                                                      W1t, b1, W2t, b2, W3, b3, out);
}

// Round 18
// 390.184 us; speedup vs baseline: 1.1904x; 1.0667x over previous
//
#include <hip/hip_runtime.h>

// Problem constants (from reference)
constexpr int KDIM  = 128;
constexpr int NEXER = 16384;
constexpr int NNODE = KDIM + NEXER;   // 16512
constexpr int NEDGE = 400000;
constexpr int NBATCH = 4096;
constexpr int NHIST = NBATCH * 50;    // 204800

// CSR build partitioning
constexpr int NCHUNK = 32;
constexpr int CHSZ   = NEDGE / NCHUNK;  // 12500
constexpr int RHALF  = NNODE / 2;       // 8256 -> 33 KB LDS hist

// h stored as fp8 e4m3 scaled by HSCALE; 1/HSCALE folded into csr weights.
constexpr float HSCALE = 32.f;
constexpr float HINV   = 1.f / 32.f;

typedef __attribute__((ext_vector_type(8))) short bf16x8;
typedef __attribute__((ext_vector_type(4))) float f32x4;
typedef __attribute__((ext_vector_type(2))) float f32x2;

__device__ __forceinline__ float sigmoidf(float x) {
    return 1.0f / (1.0f + __expf(-x));
}

// round-to-nearest-even fp32 -> bf16 (as ushort)
__device__ __forceinline__ ushort f2bf(float f) {
    uint x = __float_as_uint(f);
    uint r = (x + 0x7FFFu + ((x >> 16) & 1u)) >> 16;
    return (ushort)r;
}

// ---- fp8 e4m3 helpers (HW conversion on gfx950, guarded fallback) ----
#if __has_builtin(__builtin_amdgcn_cvt_pk_fp8_f32) && __has_builtin(__builtin_amdgcn_cvt_pk_f32_fp8)
#define HAVE_HW_FP8 1
#else
#define HAVE_HW_FP8 0
#endif

__device__ __forceinline__ uint fp8_encode1(float f) {
    // manual e4m3fn encode (fallback only)
    uint sign = (__float_as_uint(f) >> 31) << 7;
    float a = fabsf(f);
    if (a >= 448.f) return sign | 0x7E;
    if (a < 0.0009765625f) return sign;           // < half min-subnormal
    if (a >= 0.015625f) {
        int e; float m = frexpf(a, &e);           // a = m*2^e, m in [0.5,1)
        int E = e + 6;
        int q = (int)rintf(m * 16.f);             // [8,16]
        if (q == 16) { q = 8; E += 1; }
        if (E >= 16) return sign | 0x7E;
        return sign | ((uint)E << 3) | (uint)(q - 8);
    } else {
        int q = (int)rintf(a * 512.f);
        if (q > 7) return sign | (1u << 3);
        return sign | (uint)q;
    }
}

__device__ __forceinline__ float fp8_decode1(uint b) {
    uint s = b >> 7, e = (b >> 3) & 15, m = b & 7;
    float v = (e == 0) ? (float)m * 0.001953125f
                       : ldexpf((float)(8 + m), (int)e - 10);
    return s ? -v : v;
}

// encode pair (a,b) into low 16 bits of a uint
__device__ __forceinline__ ushort fp8_pk2(float a, float b) {
#if HAVE_HW_FP8
    return (ushort)(__builtin_amdgcn_cvt_pk_fp8_f32(a, b, 0, false) & 0xFFFF);
#else
    return (ushort)(fp8_encode1(a) | (fp8_encode1(b) << 8));
#endif
}

__device__ __forceinline__ void accum8f8(float* ax, uint2 p, int wbits) {
    float w = __int_as_float(wbits);
#if HAVE_HW_FP8
    f32x2 v0 = __builtin_amdgcn_cvt_pk_f32_fp8(p.x, false);
    f32x2 v1 = __builtin_amdgcn_cvt_pk_f32_fp8(p.x, true);
    f32x2 v2 = __builtin_amdgcn_cvt_pk_f32_fp8(p.y, false);
    f32x2 v3 = __builtin_amdgcn_cvt_pk_f32_fp8(p.y, true);
    ax[0] += w * v0.x; ax[1] += w * v0.y;
    ax[2] += w * v1.x; ax[3] += w * v1.y;
    ax[4] += w * v2.x; ax[5] += w * v2.y;
    ax[6] += w * v3.x; ax[7] += w * v3.y;
#else
    ax[0] += w * fp8_decode1(p.x & 255);        ax[1] += w * fp8_decode1((p.x >> 8) & 255);
    ax[2] += w * fp8_decode1((p.x >> 16) & 255); ax[3] += w * fp8_decode1(p.x >> 24);
    ax[4] += w * fp8_decode1(p.y & 255);        ax[5] += w * fp8_decode1((p.y >> 8) & 255);
    ax[6] += w * fp8_decode1((p.y >> 16) & 255); ax[7] += w * fp8_decode1(p.y >> 24);
#endif
}

__device__ __forceinline__ float hclamp(float v) {
    return fmaxf(fminf(v, 440.f), -440.f);
}

__device__ __forceinline__ void accum8(float* ax, uint4 p, int wbits) {
    float w = __int_as_float(wbits);
    ax[0] += w * __uint_as_float(p.x << 16);
    ax[1] += w * __uint_as_float(p.x & 0xFFFF0000u);
    ax[2] += w * __uint_as_float(p.y << 16);
    ax[3] += w * __uint_as_float(p.y & 0xFFFF0000u);
    ax[4] += w * __uint_as_float(p.z << 16);
    ax[5] += w * __uint_as_float(p.z & 0xFFFF0000u);
    ax[6] += w * __uint_as_float(p.w << 16);
    ax[7] += w * __uint_as_float(p.w & 0xFFFF0000u);
}

// ---------------------------------------------------------------- fused prep: entity->fp8/full_acc ; gcnW -> Wt ; head weights
constexpr int EMB_BLOCKS = (NNODE * KDIM / 2) / 256;            // 4128
constexpr int W_BLOCKS   = 16 * 12;                             // 192
constexpr int HEAD_ELEMS = 512 * 128 + 224 * 512;               // 180224
constexpr int HEAD_BLOCKS = (HEAD_ELEMS + 255) / 256;           // 704
__global__ __launch_bounds__(256) void prep_all_kernel(
    const float* __restrict__ entity, ushort* __restrict__ h8,
    float* __restrict__ full_acc,
    const float* __restrict__ W, ushort* __restrict__ Wt,
    const float* __restrict__ W1, const float* __restrict__ W2,
    ushort* __restrict__ W1t, ushort* __restrict__ W2t)
{
    __shared__ float tile[32][33];
    int bx = blockIdx.x;
    if (bx < EMB_BLOCKS) {
        int idx = bx * 256 + threadIdx.x;
        float2 v = ((const float2*)entity)[idx];
        ((float2*)full_acc)[idx] = v;
        h8[idx] = fp8_pk2(hclamp(v.x * HSCALE), hclamp(v.y * HSCALE));
        return;
    }
    bx -= EMB_BLOCKS;
    if (bx < W_BLOCKS) {
        int gl = bx >> 4;                  // 0..11
        int tl = bx & 15;
        int tk = tl >> 2, tn = tl & 3;
        int k0 = tk * 32, n0 = tn * 32;
        int tx = threadIdx.x & 31, ty = threadIdx.x >> 5;  // ty 0..7
        const float* src = W + ((size_t)gl << 14);
        #pragma unroll
        for (int i = 0; i < 4; ++i) {
            int k = ty * 4 + i;
            tile[k][tx] = src[(k0 + k) * 128 + n0 + tx];
        }
        __syncthreads();
        ushort* dst = Wt + ((size_t)gl << 14);
        #pragma unroll
        for (int i = 0; i < 4; ++i) {
            int n = ty * 4 + i;
            dst[(n0 + n) * 128 + k0 + tx] = f2bf(tile[tx][n]);
        }
        return;
    }
    bx -= W_BLOCKS;
    int idx = bx * 256 + threadIdx.x;
    if (idx < 512 * 128) {
        int n = idx >> 7, k = idx & 127;
        W1t[idx] = f2bf(W1[k * 512 + n]);
    }
    int idx2 = idx - 512 * 128;
    if (idx2 >= 0 && idx2 < 224 * 512) {
        int n = idx2 >> 9, k = idx2 & 511;
        W2t[idx2] = f2bf(n < 216 ? W2[k * 216 + n] : 0.f);
    }
}

// ---------------------------------------------------------------- partial degree hist + per-edge rank (dense writes)
// grid: (NCHUNK, 2, 6)  z = g*2+side (side 0=src,1=dst)
__global__ __launch_bounds__(256) void count_part_kernel(
    const int* __restrict__ s0, const int* __restrict__ d0,
    const int* __restrict__ s1, const int* __restrict__ d1,
    const int* __restrict__ s2, const int* __restrict__ d2,
    int* __restrict__ partial,   // [6][NCHUNK][NNODE]
    ushort* __restrict__ rank)   // [3][NEDGE] (dst side only)
{
    __shared__ int hist[RHALF];
    int c = blockIdx.x, r = blockIdx.y, gs = blockIdx.z;
    const int* arr = (gs == 0) ? s0 : (gs == 1) ? d0 : (gs == 2) ? s1
                   : (gs == 3) ? d1 : (gs == 4) ? s2 : d2;
    for (int i = threadIdx.x; i < RHALF; i += 256) hist[i] = 0;
    __syncthreads();
    int base = r * RHALF;
    const int* p = arr + c * CHSZ;
    if (gs & 1) {
        ushort* rk = rank + (size_t)(gs >> 1) * NEDGE + c * CHSZ;
        for (int i = threadIdx.x; i < CHSZ; i += 256) {
            int v = p[i] - base;
            if ((unsigned)v < (unsigned)RHALF)
                rk[i] = (ushort)atomicAdd(&hist[v], 1);
        }
    } else {
        for (int i = threadIdx.x; i < CHSZ; i += 256) {
            int v = p[i] - base;
            if ((unsigned)v < (unsigned)RHALF) atomicAdd(&hist[v], 1);
        }
    }
    __syncthreads();
    int* outp = partial + ((size_t)gs * NCHUNK + c) * NNODE + base;
    for (int i = threadIdx.x; i < RHALF; i += 256) outp[i] = hist[i];
}

// ---------------------------------------------------------------- sum partials -> cnt[6][NNODE] (degrees, for norm)
__global__ __launch_bounds__(256) void sum_kernel(
    const int* __restrict__ partial, int* __restrict__ cnt)
{
    int idx = blockIdx.x * 256 + threadIdx.x;
    if (idx >= 6 * NNODE) return;
    int gs = idx / NNODE, node = idx - gs * NNODE;
    const int* pp = partial + (size_t)gs * NCHUNK * NNODE + node;
    int s = 0;
    #pragma unroll 8
    for (int c = 0; c < NCHUNK; ++c) s += pp[c * NNODE];
    cnt[idx] = s;
}

// ---------------------------------------------------------------- row_ptr scan (reads cnt dst-planes)
__global__ __launch_bounds__(256) void scan_kernel(
    const int* __restrict__ cnt, int* __restrict__ rp)
{
    int g = blockIdx.x;
    const int* c = cnt + (g * 2 + 1) * NNODE;   // dst side
    int* r = rp + g * (NNODE + 1);
    __shared__ int part[256];
    int t = threadIdx.x;
    constexpr int CH = (NNODE + 255) / 256;  // 65
    int lo = t * CH;
    int hi = lo + CH; if (hi > NNODE) hi = NNODE;
    int s = 0;
    for (int i = lo; i < hi; ++i) s += c[i];
    part[t] = s;
    __syncthreads();
    for (int off = 1; off < 256; off <<= 1) {
        int v = part[t];
        if (t >= off) v += part[t - off];
        __syncthreads();
        part[t] = v;
        __syncthreads();
    }
    int run = (t == 0) ? 0 : part[t - 1];
    for (int i = lo; i < hi; ++i) { r[i] = run; run += c[i]; }
    if (t == 255) r[NNODE] = part[255];
}

// ---------------------------------------------------------------- chunk_base[g][c][node] = rp[node] + excl-scan of dst partials over c
__global__ __launch_bounds__(256) void base_kernel(
    const int* __restrict__ partial, const int* __restrict__ rp,
    int* __restrict__ chunk_base)
{
    int idx = blockIdx.x * 256 + threadIdx.x;
    if (idx >= 3 * NNODE) return;
    int g = idx / NNODE, node = idx - g * NNODE;
    int running = rp[g * (NNODE + 1) + node];
    const int* pp = partial + (size_t)(g * 2 + 1) * NCHUNK * NNODE + node;
    int* ob = chunk_base + (size_t)g * NCHUNK * NNODE + node;
    #pragma unroll 8
    for (int c = 0; c < NCHUNK; ++c) { ob[c * NNODE] = running; running += pp[c * NNODE]; }
}

// ---------------------------------------------------------------- CSR fill: pure parallel scatter (1 thread / edge)
// Packed 4-byte edge: low 16 bits = src node (<32768), high 16 bits = bf16 weight
// (rsqrt norm * 1/HSCALE to undo the fp8 h scaling).
__global__ __launch_bounds__(256) void fill_scatter_kernel(
    const int* __restrict__ s0, const int* __restrict__ d0,
    const int* __restrict__ s1, const int* __restrict__ d1,
    const int* __restrict__ s2, const int* __restrict__ d2,
    const int* __restrict__ cnt, const int* __restrict__ chunk_base,
    const ushort* __restrict__ rank, uint* __restrict__ csr_packed)
{
    int e = blockIdx.x * 256 + threadIdx.x;
    int g = blockIdx.y;
    if (e >= NEDGE) return;
    const int* s = (g == 0) ? s0 : (g == 1) ? s1 : s2;
    const int* d = (g == 0) ? d0 : (g == 1) ? d1 : d2;
    int sv = s[e], dv = d[e];
    int c = e / CHSZ;
    int pos = chunk_base[((size_t)g * NCHUNK + c) * NNODE + dv]
            + (int)rank[(size_t)g * NEDGE + e];
    int a = cnt[(g * 2 + 0) * NNODE + sv]; if (a < 1) a = 1;
    int b = cnt[(g * 2 + 1) * NNODE + dv]; if (b < 1) b = 1;
    float w = rsqrtf((float)a * (float)b) * HINV;
    csr_packed[(size_t)g * NEDGE + pos] = (uint)sv | ((uint)f2bf(w) << 16);
}

// ---------------------------------------------------------------- CSR gather (fp8 h, 4B packed edges), 3-stage pipeline:
// grid (NNODE/16, 3): wave = 4 rows, 16 lanes/row, lane owns one uint2 (8 fp8 cols).
// Pipeline: descs batch k+2 || rows batch k+1 || accumulate batch k.
__global__ __launch_bounds__(256) void gather_kernel(
    const ushort* __restrict__ h8, const uint* __restrict__ csr_packed,
    const int* __restrict__ rp, ushort* __restrict__ agg)
{
    int t = threadIdx.x;
    int wave = t >> 6, lane = t & 63;
    int sub = lane >> 4, li = lane & 15;
    int g = blockIdx.y;
    int row = blockIdx.x * 16 + wave * 4 + sub;
    int js = rp[g * (NNODE + 1) + row];
    int je = rp[g * (NNODE + 1) + row + 1];
    const uint* ep = csr_packed + (size_t)g * NEDGE;
    const uint2* hb2 = (const uint2*)h8;    // one row = 128 fp8 = 16 uint2
    float ax[8];
    #pragma unroll
    for (int i = 0; i < 8; ++i) ax[i] = 0.f;
    int j = js;
    if (je - js >= 8) {
        uint a0 = ep[j], a1 = ep[j + 1], a2 = ep[j + 2], a3 = ep[j + 3];
        uint b0 = ep[j + 4], b1 = ep[j + 5], b2 = ep[j + 6], b3 = ep[j + 7];
        uint2 ra0 = hb2[(size_t)(a0 & 0x7FFFu) * 16 + li];
        uint2 ra1 = hb2[(size_t)(a1 & 0x7FFFu) * 16 + li];
        uint2 ra2 = hb2[(size_t)(a2 & 0x7FFFu) * 16 + li];
        uint2 ra3 = hb2[(size_t)(a3 & 0x7FFFu) * 16 + li];
        j += 8;
        while (j + 3 < je) {
            uint c0 = ep[j], c1 = ep[j + 1], c2 = ep[j + 2], c3 = ep[j + 3];
            uint2 rb0 = hb2[(size_t)(b0 & 0x7FFFu) * 16 + li];
            uint2 rb1 = hb2[(size_t)(b1 & 0x7FFFu) * 16 + li];
            uint2 rb2 = hb2[(size_t)(b2 & 0x7FFFu) * 16 + li];
            uint2 rb3 = hb2[(size_t)(b3 & 0x7FFFu) * 16 + li];
            accum8f8(ax, ra0, (int)(a0 & 0xFFFF0000u));
            accum8f8(ax, ra1, (int)(a1 & 0xFFFF0000u));
            accum8f8(ax, ra2, (int)(a2 & 0xFFFF0000u));
            accum8f8(ax, ra3, (int)(a3 & 0xFFFF0000u));
            a0 = b0; a1 = b1; a2 = b2; a3 = b3;
            b0 = c0; b1 = c1; b2 = c2; b3 = c3;
            ra0 = rb0; ra1 = rb1; ra2 = rb2; ra3 = rb3;
            j += 4;
        }
        // drain: A has rows; B needs rows
        uint2 rb0 = hb2[(size_t)(b0 & 0x7FFFu) * 16 + li];
        uint2 rb1 = hb2[(size_t)(b1 & 0x7FFFu) * 16 + li];
        uint2 rb2 = hb2[(size_t)(b2 & 0x7FFFu) * 16 + li];
        uint2 rb3 = hb2[(size_t)(b3 & 0x7FFFu) * 16 + li];
        accum8f8(ax, ra0, (int)(a0 & 0xFFFF0000u));
        accum8f8(ax, ra1, (int)(a1 & 0xFFFF0000u));
        accum8f8(ax, ra2, (int)(a2 & 0xFFFF0000u));
        accum8f8(ax, ra3, (int)(a3 & 0xFFFF0000u));
        accum8f8(ax, rb0, (int)(b0 & 0xFFFF0000u));
        accum8f8(ax, rb1, (int)(b1 & 0xFFFF0000u));
        accum8f8(ax, rb2, (int)(b2 & 0xFFFF0000u));
        accum8f8(ax, rb3, (int)(b3 & 0xFFFF0000u));
    }
    for (; j < je; ++j) {
        uint e0 = ep[j];
        uint2 p0 = hb2[(size_t)(e0 & 0x7FFFu) * 16 + li];
        accum8f8(ax, p0, (int)(e0 & 0xFFFF0000u));
    }
    uint4 o;
    o.x = (uint)f2bf(ax[0]) | ((uint)f2bf(ax[1]) << 16);
    o.y = (uint)f2bf(ax[2]) | ((uint)f2bf(ax[3]) << 16);
    o.z = (uint)f2bf(ax[4]) | ((uint)f2bf(ax[5]) << 16);
    o.w = (uint)f2bf(ax[6]) | ((uint)f2bf(ax[7]) << 16);
    ((uint4*)agg)[((size_t)g * NNODE + row) * 16 + li] = o;
}

// ---------------------------------------------------------------- MFMA GEMM: h_next = sum_g agg_g @ W[g,l] + bsum
// epilogue: h8 = fp8(v*HSCALE) ; layer 2: disc_acc = v ; layer 3: disc_bf = bf16((disc_acc+v)*0.5)
__global__ __launch_bounds__(256) void gemm_kernel(
    const ushort* __restrict__ agg, const ushort* __restrict__ Wt,
    const float* __restrict__ gcnB, int layer,
    ushort* __restrict__ h8, float* __restrict__ full_acc,
    float* __restrict__ disc_acc, ushort* __restrict__ disc_bf)
{
    __shared__ ushort Wlds[128 * 136];   // pad 136: 2-way max bank aliasing (free)
    __shared__ float bsum[128];
    int t = threadIdx.x;
    int wave = t >> 6, lane = t & 63;
    int R0 = blockIdx.x * 64;
    if (t < 128)
        bsum[t] = gcnB[(0 * 4 + layer) * 128 + t] + gcnB[(1 * 4 + layer) * 128 + t]
                + gcnB[(2 * 4 + layer) * 128 + t];
    int m = lane & 15, q = lane >> 4;
    int arow = R0 + wave * 16 + m;
    f32x4 acc[8];
    #pragma unroll
    for (int n = 0; n < 8; ++n) acc[n] = (f32x4){0.f, 0.f, 0.f, 0.f};
    for (int g = 0; g < 3; ++g) {
        __syncthreads();
        const ushort* src = Wt + ((size_t)(g * 4 + layer) << 14);
        for (int i = t; i < 2048; i += 256) {          // 128 rows x 16 uint4
            int row = i >> 4, c = i & 15;
            *(uint4*)&Wlds[row * 136 + c * 8] = *(const uint4*)(src + row * 128 + c * 8);
        }
        __syncthreads();
        const ushort* ap = agg + ((size_t)g * NNODE + arow) * 128 + q * 8;
        bf16x8 af[4];
        #pragma unroll
        for (int k = 0; k < 4; ++k) af[k] = *(const bf16x8*)(ap + k * 32);
        #pragma unroll
        for (int n = 0; n < 8; ++n) {
            const ushort* bp = &Wlds[(n * 16 + m) * 136 + q * 8];
            #pragma unroll
            for (int k = 0; k < 4; ++k) {
                bf16x8 bfr = *(const bf16x8*)(bp + k * 32);
                acc[n] = __builtin_amdgcn_mfma_f32_16x16x32_bf16(af[k], bfr, acc[n], 0, 0, 0);
            }
        }
    }
    __syncthreads();
    float* stage = (float*)Wlds;       // reuse LDS (34816 B >= 32768 B)
    #pragma unroll
    for (int n = 0; n < 8; ++n) {
        #pragma unroll
        for (int r = 0; r < 4; ++r)
            stage[(wave * 16 + q * 4 + r) * 128 + n * 16 + m] = acc[n][r];
    }
    __syncthreads();
    for (int idx = t; idx < 64 * 64; idx += 256) {     // col-pair granularity
        int row = idx >> 6, cp = idx & 63;
        int gr = R0 + row;
        int c0 = cp * 2;
        float v0 = stage[row * 128 + c0] + bsum[c0];
        float v1 = stage[row * 128 + c0 + 1] + bsum[c0 + 1];
        size_t o = (size_t)gr * 128 + c0;
        float2 f = *(float2*)&full_acc[o];
        f.x += v0; f.y += v1;
        *(float2*)&full_acc[o] = f;
        h8[(size_t)gr * 64 + cp] = fp8_pk2(hclamp(v0 * HSCALE), hclamp(v1 * HSCALE));
        if (gr >= KDIM) {
            size_t od = (size_t)(gr - KDIM) * 64 + cp;
            if (layer == 2) {
                *(float2*)&disc_acc[od * 2] = make_float2(v0, v1);
            } else if (layer == 3) {
                float2 dv = *(const float2*)&disc_acc[od * 2];
                ((uint*)disc_bf)[od] = (uint)f2bf((dv.x + v0) * 0.5f)
                                     | ((uint)f2bf((dv.y + v1) * 0.5f) << 16);
            }
        }
    }
}

// ---------------------------------------------------------------- fused pool + head: 16 batch rows per block
__global__ __launch_bounds__(256) void pool_head_kernel(
    const ushort* __restrict__ disc_bf, const int* __restrict__ hist,
    const int* __restrict__ segids,
    const float* __restrict__ full,
    const float* __restrict__ fsW, const float* __restrict__ fsB,
    const float* __restrict__ feW, const float* __restrict__ feB,
    const float* __restrict__ disc_emb, const int* __restrict__ exer_id,
    const float* __restrict__ kn,
    const ushort* __restrict__ W1t, const float* __restrict__ b1,
    const ushort* __restrict__ W2t, const float* __restrict__ b2,
    const float* __restrict__ W3, const float* __restrict__ b3,
    float* __restrict__ out)
{
    __shared__ ushort xsl[16][136];   // x bf16, A-layout readable
    __shared__ ushort o1l[16][520];   // o1 bf16
    __shared__ float  o2l[16][228];   // o2 f32
    __shared__ float  cwl[256];       // concept @ W[K:], scaled 0.2
    __shared__ float  sdl[16];        // pooled-stu dot fsW[:K]
    int t = threadIdx.x, wave = t >> 6, lane = t & 63;
    int b0 = blockIdx.x * 16;
    float fsb = fsB[0], feb = feB[0];
    // ---- stage A1: cw (redundant per block; 128-len dot per thread)
    {
        int j = t & 127;
        const float* w = (t < 128) ? (fsW + KDIM) : (feW + KDIM);
        const float* row = full + (size_t)j * KDIM;
        float s = 0.f;
        for (int k = 0; k < KDIM; ++k) s += row[k] * w[k];
        cwl[t] = s * 0.2f;   // fold full/5
    }
    // ---- stage A2: history pooling -> sd (wave = 4 rows, 16 lanes/row)
    {
        int sub = lane >> 4, li = lane & 15;
        int rr = wave * 4 + sub;
        int b = b0 + rr;
        auto bsearch = [&](int key) {
            int lo = 0, hi = NHIST;
            while (lo < hi) {
                int m = (lo + hi) >> 1;
                if (segids[m] < key) lo = m + 1; else hi = m;
            }
            return lo;
        };
        int js = bsearch(b), je = bsearch(b + 1);
        const uint4* db4 = (const uint4*)disc_bf;
        float ax[8];
        #pragma unroll
        for (int i = 0; i < 8; ++i) ax[i] = 0.f;
        int one = __float_as_int(1.0f);
        int j = js;
        if (je - js >= 8) {
            int a0 = hist[j], a1 = hist[j + 1], a2 = hist[j + 2], a3 = hist[j + 3];
            int b0i = hist[j + 4], b1i = hist[j + 5], b2i = hist[j + 6], b3i = hist[j + 7];
            uint4 ra0 = db4[(size_t)a0 * 16 + li];
            uint4 ra1 = db4[(size_t)a1 * 16 + li];
            uint4 ra2 = db4[(size_t)a2 * 16 + li];
            uint4 ra3 = db4[(size_t)a3 * 16 + li];
            j += 8;
            while (j + 3 < je) {
                int c0 = hist[j], c1 = hist[j + 1], c2 = hist[j + 2], c3 = hist[j + 3];
                uint4 rb0 = db4[(size_t)b0i * 16 + li];
                uint4 rb1 = db4[(size_t)b1i * 16 + li];
                uint4 rb2 = db4[(size_t)b2i * 16 + li];
                uint4 rb3 = db4[(size_t)b3i * 16 + li];
                accum8(ax, ra0, one); accum8(ax, ra1, one);
                accum8(ax, ra2, one); accum8(ax, ra3, one);
                b0i = c0; b1i = c1; b2i = c2; b3i = c3;
                ra0 = rb0; ra1 = rb1; ra2 = rb2; ra3 = rb3;
                j += 4;
            }
            uint4 rb0 = db4[(size_t)b0i * 16 + li];
            uint4 rb1 = db4[(size_t)b1i * 16 + li];
            uint4 rb2 = db4[(size_t)b2i * 16 + li];
            uint4 rb3 = db4[(size_t)b3i * 16 + li];
            accum8(ax, ra0, one); accum8(ax, ra1, one);
            accum8(ax, ra2, one); accum8(ax, ra3, one);
            accum8(ax, rb0, one); accum8(ax, rb1, one);
            accum8(ax, rb2, one); accum8(ax, rb3, one);
        }
        for (; j < je; ++j) {
            uint4 p = db4[(size_t)hist[j] * 16 + li];
            accum8(ax, p, one);
        }
        float c = (float)(je - js); if (c < 1.f) c = 1.f;
        float inv = 1.f / c;
        float sd = 0.f;
        #pragma unroll
        for (int k = 0; k < 8; ++k) sd += ax[k] * inv * fsW[li * 8 + k];
        #pragma unroll
        for (int o = 8; o > 0; o >>= 1) sd += __shfl_xor(sd, o, 16);
        if (li == 0) sdl[rr] = sd;
    }
    __syncthreads();
    // ---- stage B: build x rows (bf16)
    #pragma unroll
    for (int i = 0; i < 4; ++i) {
        int rr = wave * 4 + i;
        int b = b0 + rr;
        int eid = exer_id[b];
        const float* er = full + (size_t)(KDIM + eid) * KDIM;
        float ed = er[lane] * feW[lane] + er[lane + 64] * feW[lane + 64];
        #pragma unroll
        for (int o = 32; o > 0; o >>= 1) ed += __shfl_xor(ed, o);
        ed *= 0.2f;   // fold full/5
        float sd = sdl[rr];
        float edisc = 10.f * sigmoidf(disc_emb[eid]);
        for (int j = lane; j < KDIM; j += 64) {
            float prof = sigmoidf(sd + cwl[j] + fsb);
            float diff = sigmoidf(ed + cwl[KDIM + j] + feb);
            xsl[rr][j] = f2bf(edisc * (prof - diff) * kn[(size_t)b * KDIM + j]);
        }
    }
    __syncthreads();
    int m = lane & 15, q = lane >> 4;
    // ---- layer 1 MFMA: wave handles n in [wave*128, wave*128+128)
    bf16x8 af[4];
    #pragma unroll
    for (int kk = 0; kk < 4; ++kk) af[kk] = *(const bf16x8*)&xsl[m][kk * 32 + q * 8];
    f32x4 acc[8];
    #pragma unroll
    for (int n = 0; n < 8; ++n) acc[n] = (f32x4){0.f, 0.f, 0.f, 0.f};
    const ushort* w1base = W1t + (size_t)(wave * 128) * 128;
    #pragma unroll
    for (int nt = 0; nt < 8; ++nt) {
        const ushort* bp = w1base + (nt * 16 + m) * 128 + q * 8;
        #pragma unroll
        for (int kk = 0; kk < 4; ++kk) {
            bf16x8 bf = *(const bf16x8*)(bp + kk * 32);
            acc[nt] = __builtin_amdgcn_mfma_f32_16x16x32_bf16(af[kk], bf, acc[nt], 0, 0, 0);
        }
    }
    #pragma unroll
    for (int nt = 0; nt < 8; ++nt) {
        int n = wave * 128 + nt * 16 + m;
        float bv = b1[n];
        #pragma unroll
        for (int r = 0; r < 4; ++r)
            o1l[q * 4 + r][n] = f2bf(sigmoidf(acc[nt][r] + bv));
    }
    __syncthreads();
    // ---- layer 2 MFMA: 14 n-tiles distributed: wave w takes nt = w, w+4, w+8, (w+12)
    int ntt = (wave < 2) ? 4 : 3;
    f32x4 acc2[4];
    #pragma unroll
    for (int i = 0; i < 4; ++i) acc2[i] = (f32x4){0.f, 0.f, 0.f, 0.f};
    #pragma unroll 4
    for (int kk = 0; kk < 16; ++kk) {
        bf16x8 a2 = *(const bf16x8*)&o1l[m][kk * 32 + q * 8];
        #pragma unroll
        for (int tt = 0; tt < 4; ++tt) {
            if (tt < ntt) {
                int nt = wave + 4 * tt;
                bf16x8 bf = *(const bf16x8*)(W2t + (size_t)(nt * 16 + m) * 512 + kk * 32 + q * 8);
                acc2[tt] = __builtin_amdgcn_mfma_f32_16x16x32_bf16(a2, bf, acc2[tt], 0, 0, 0);
            }
        }
    }
    #pragma unroll
    for (int tt = 0; tt < 4; ++tt) {
        if (tt < ntt) {
            int nt = wave + 4 * tt;
            int n = nt * 16 + m;
            if (n < 216) {
                float bv = b2[n];
                #pragma unroll
                for (int r = 0; r < 4; ++r)
                    o2l[q * 4 + r][n] = sigmoidf(acc2[tt][r] + bv);
            }
        }
    }
    __syncthreads();
    // ---- layer 3: 16-lane dot per row
    int sub = lane >> 4, li = lane & 15;
    int rr = wave * 4 + sub;
    float dot = 0.f;
    for (int p = li; p < 216; p += 16) dot += o2l[rr][p] * W3[p];
    #pragma unroll
    for (int o = 8; o > 0; o >>= 1) dot += __shfl_xor(dot, o, 16);
    if (li == 0) out[b0 + rr] = sigmoidf(dot + b3[0]);
}

// ================================================================ host
extern "C" void kernel_launch(void* const* d_in, const int* in_sizes, int n_in,
                              void* d_out, int out_size, void* d_ws, size_t ws_size,
                              hipStream_t stream)
{
    (void)in_sizes; (void)n_in; (void)out_size; (void)ws_size;
    const float* entity = (const float*)d_in[0];
    const float* gcnW   = (const float*)d_in[1];
    const float* gcnB   = (const float*)d_in[2];
    const float* fsW    = (const float*)d_in[3];
    const float* fsB    = (const float*)d_in[4];
    const float* feW    = (const float*)d_in[5];
    const float* feB    = (const float*)d_in[6];
    const float* disc_emb = (const float*)d_in[7];
    const float* W1 = (const float*)d_in[8];
    const float* b1 = (const float*)d_in[9];
    const float* W2 = (const float*)d_in[10];
    const float* b2 = (const float*)d_in[11];
    const float* W3 = (const float*)d_in[12];
    const float* b3 = (const float*)d_in[13];
    const int* s0 = (const int*)d_in[14];
    const int* d0 = (const int*)d_in[15];
    const int* s1 = (const int*)d_in[16];
    const int* d1 = (const int*)d_in[17];
    const int* s2 = (const int*)d_in[18];
    const int* d2 = (const int*)d_in[19];
    const int* exer_id = (const int*)d_in[21];
    const float* kn = (const float*)d_in[22];
    const int* hist = (const int*)d_in[23];
    const int* segid = (const int*)d_in[24];
    float* out = (float*)d_out;

    char* wsb = (char*)d_ws;
    size_t off = 0;
    auto alloc = [&](size_t bytes) -> void* {
        void* p = wsb + off;
        off = (off + bytes + 255) & ~(size_t)255;
        return p;
    };
    int*    partial   = (int*)alloc((size_t)6 * NCHUNK * NNODE * sizeof(int));   // 12.7 MB
    int*    cnt       = (int*)alloc((size_t)6 * NNODE * sizeof(int));
    int*    rp        = (int*)alloc((size_t)3 * (NNODE + 1) * sizeof(int));
    int*    chunk_base= (int*)alloc((size_t)3 * NCHUNK * NNODE * sizeof(int));   // 6.3 MB
    ushort* rank      = (ushort*)alloc((size_t)3 * NEDGE * sizeof(ushort));      // 2.4 MB
    uint*   csr_packed= (uint*)alloc((size_t)3 * NEDGE * sizeof(uint));          // 4.8 MB
    ushort* h8        = (ushort*)alloc((size_t)NNODE * KDIM);                    // fp8: 2.1 MB (ushort = 2 fp8)
    ushort* agg       = (ushort*)alloc((size_t)3 * NNODE * KDIM * sizeof(ushort));
    ushort* Wt        = (ushort*)alloc((size_t)3 * 4 * KDIM * KDIM * sizeof(ushort));
    ushort* W1t       = (ushort*)alloc((size_t)512 * 128 * sizeof(ushort));
    ushort* W2t       = (ushort*)alloc((size_t)224 * 512 * sizeof(ushort));
    float*  full_acc  = (float*)alloc((size_t)NNODE * KDIM * sizeof(float));
    float*  disc_acc  = (float*)alloc((size_t)NEXER * KDIM * sizeof(float));
    ushort* disc_bf   = (ushort*)alloc((size_t)NEXER * KDIM * sizeof(ushort));

    prep_all_kernel<<<EMB_BLOCKS + W_BLOCKS + HEAD_BLOCKS, 256, 0, stream>>>(
        entity, h8, full_acc, gcnW, Wt, W1, W2, W1t, W2t);

    // CSR build: LDS-hist counting (ranks recorded), then fully parallel scatter
    count_part_kernel<<<dim3(NCHUNK, 2, 6), 256, 0, stream>>>(s0, d0, s1, d1, s2, d2,
                                                              partial, rank);
    sum_kernel<<<(6 * NNODE + 255) / 256, 256, 0, stream>>>(partial, cnt);
    scan_kernel<<<3, 256, 0, stream>>>(cnt, rp);
    base_kernel<<<(3 * NNODE + 255) / 256, 256, 0, stream>>>(partial, rp, chunk_base);
    fill_scatter_kernel<<<dim3((NEDGE + 255) / 256, 3), 256, 0, stream>>>(
        s0, d0, s1, d1, s2, d2, cnt, chunk_base, rank, csr_packed);

    for (int l = 0; l < 4; ++l) {
        gather_kernel<<<dim3(NNODE / 16, 3), 256, 0, stream>>>(h8, csr_packed, rp, agg);
        gemm_kernel<<<NNODE / 64, 256, 0, stream>>>(agg, Wt, gcnB, l, h8, full_acc,
                                                    disc_acc, disc_bf);
    }

    pool_head_kernel<<<NBATCH / 16, 256, 0, stream>>>(disc_bf, hist, segid,
                                                      full_acc, fsW, fsB, feW, feB,
                                                      disc_emb, exer_id, kn,
                                                      W1t, b1, W2t, b2, W3, b3, out);
}

// Round 19
// 387.622 us; speedup vs baseline: 1.1983x; 1.0066x over previous
//
#include <hip/hip_runtime.h>

// Problem constants (from reference)
constexpr int KDIM  = 128;
constexpr int NEXER = 16384;
constexpr int NNODE = KDIM + NEXER;   // 16512
constexpr int NEDGE = 400000;
constexpr int NBATCH = 4096;
constexpr int NHIST = NBATCH * 50;    // 204800

// CSR build partitioning
constexpr int NCHUNK = 32;
constexpr int CHSZ   = NEDGE / NCHUNK;  // 12500
constexpr int RHALF  = NNODE / 2;       // 8256 -> 33 KB LDS hist

// h (and disc) stored as fp8 e4m3 scaled by HSCALE; 1/HSCALE folded downstream.
constexpr float HSCALE = 32.f;
constexpr float HINV   = 1.f / 32.f;

typedef __attribute__((ext_vector_type(8))) short bf16x8;
typedef __attribute__((ext_vector_type(4))) float f32x4;
typedef __attribute__((ext_vector_type(2))) float f32x2;

__device__ __forceinline__ float sigmoidf(float x) {
    return 1.0f / (1.0f + __expf(-x));
}

// round-to-nearest-even fp32 -> bf16 (as ushort)
__device__ __forceinline__ ushort f2bf(float f) {
    uint x = __float_as_uint(f);
    uint r = (x + 0x7FFFu + ((x >> 16) & 1u)) >> 16;
    return (ushort)r;
}

// ---- fp8 e4m3 helpers (HW conversion on gfx950, guarded fallback) ----
#if __has_builtin(__builtin_amdgcn_cvt_pk_fp8_f32) && __has_builtin(__builtin_amdgcn_cvt_pk_f32_fp8)
#define HAVE_HW_FP8 1
#else
#define HAVE_HW_FP8 0
#endif

__device__ __forceinline__ uint fp8_encode1(float f) {
    // manual e4m3fn encode (fallback only)
    uint sign = (__float_as_uint(f) >> 31) << 7;
    float a = fabsf(f);
    if (a >= 448.f) return sign | 0x7E;
    if (a < 0.0009765625f) return sign;           // < half min-subnormal
    if (a >= 0.015625f) {
        int e; float m = frexpf(a, &e);           // a = m*2^e, m in [0.5,1)
        int E = e + 6;
        int q = (int)rintf(m * 16.f);             // [8,16]
        if (q == 16) { q = 8; E += 1; }
        if (E >= 16) return sign | 0x7E;
        return sign | ((uint)E << 3) | (uint)(q - 8);
    } else {
        int q = (int)rintf(a * 512.f);
        if (q > 7) return sign | (1u << 3);
        return sign | (uint)q;
    }
}

__device__ __forceinline__ float fp8_decode1(uint b) {
    uint s = b >> 7, e = (b >> 3) & 15, m = b & 7;
    float v = (e == 0) ? (float)m * 0.001953125f
                       : ldexpf((float)(8 + m), (int)e - 10);
    return s ? -v : v;
}

// encode pair (a,b) into low 16 bits of a uint
__device__ __forceinline__ ushort fp8_pk2(float a, float b) {
#if HAVE_HW_FP8
    return (ushort)(__builtin_amdgcn_cvt_pk_fp8_f32(a, b, 0, false) & 0xFFFF);
#else
    return (ushort)(fp8_encode1(a) | (fp8_encode1(b) << 8));
#endif
}

__device__ __forceinline__ void accum8f8(float* ax, uint2 p, int wbits) {
    float w = __int_as_float(wbits);
#if HAVE_HW_FP8
    f32x2 v0 = __builtin_amdgcn_cvt_pk_f32_fp8(p.x, false);
    f32x2 v1 = __builtin_amdgcn_cvt_pk_f32_fp8(p.x, true);
    f32x2 v2 = __builtin_amdgcn_cvt_pk_f32_fp8(p.y, false);
    f32x2 v3 = __builtin_amdgcn_cvt_pk_f32_fp8(p.y, true);
    ax[0] += w * v0.x; ax[1] += w * v0.y;
    ax[2] += w * v1.x; ax[3] += w * v1.y;
    ax[4] += w * v2.x; ax[5] += w * v2.y;
    ax[6] += w * v3.x; ax[7] += w * v3.y;
#else
    ax[0] += w * fp8_decode1(p.x & 255);        ax[1] += w * fp8_decode1((p.x >> 8) & 255);
    ax[2] += w * fp8_decode1((p.x >> 16) & 255); ax[3] += w * fp8_decode1(p.x >> 24);
    ax[4] += w * fp8_decode1(p.y & 255);        ax[5] += w * fp8_decode1((p.y >> 8) & 255);
    ax[6] += w * fp8_decode1((p.y >> 16) & 255); ax[7] += w * fp8_decode1(p.y >> 24);
#endif
}

__device__ __forceinline__ float hclamp(float v) {
    return fmaxf(fminf(v, 440.f), -440.f);
}

// ---------------------------------------------------------------- fused prep: entity->fp8/full_acc ; gcnW -> Wt ; head weights
constexpr int EMB_BLOCKS = (NNODE * KDIM / 2) / 256;            // 4128
constexpr int W_BLOCKS   = 16 * 12;                             // 192
constexpr int HEAD_ELEMS = 512 * 128 + 224 * 512;               // 180224
constexpr int HEAD_BLOCKS = (HEAD_ELEMS + 255) / 256;           // 704
__global__ __launch_bounds__(256) void prep_all_kernel(
    const float* __restrict__ entity, ushort* __restrict__ h8,
    float* __restrict__ full_acc,
    const float* __restrict__ W, ushort* __restrict__ Wt,
    const float* __restrict__ W1, const float* __restrict__ W2,
    ushort* __restrict__ W1t, ushort* __restrict__ W2t)
{
    __shared__ float tile[32][33];
    int bx = blockIdx.x;
    if (bx < EMB_BLOCKS) {
        int idx = bx * 256 + threadIdx.x;
        float2 v = ((const float2*)entity)[idx];
        ((float2*)full_acc)[idx] = v;
        h8[idx] = fp8_pk2(hclamp(v.x * HSCALE), hclamp(v.y * HSCALE));
        return;
    }
    bx -= EMB_BLOCKS;
    if (bx < W_BLOCKS) {
        int gl = bx >> 4;                  // 0..11
        int tl = bx & 15;
        int tk = tl >> 2, tn = tl & 3;
        int k0 = tk * 32, n0 = tn * 32;
        int tx = threadIdx.x & 31, ty = threadIdx.x >> 5;  // ty 0..7
        const float* src = W + ((size_t)gl << 14);
        #pragma unroll
        for (int i = 0; i < 4; ++i) {
            int k = ty * 4 + i;
            tile[k][tx] = src[(k0 + k) * 128 + n0 + tx];
        }
        __syncthreads();
        ushort* dst = Wt + ((size_t)gl << 14);
        #pragma unroll
        for (int i = 0; i < 4; ++i) {
            int n = ty * 4 + i;
            dst[(n0 + n) * 128 + k0 + tx] = f2bf(tile[tx][n]);
        }
        return;
    }
    bx -= W_BLOCKS;
    int idx = bx * 256 + threadIdx.x;
    if (idx < 512 * 128) {
        int n = idx >> 7, k = idx & 127;
        W1t[idx] = f2bf(W1[k * 512 + n]);
    }
    int idx2 = idx - 512 * 128;
    if (idx2 >= 0 && idx2 < 224 * 512) {
        int n = idx2 >> 9, k = idx2 & 511;
        W2t[idx2] = f2bf(n < 216 ? W2[k * 216 + n] : 0.f);
    }
}

// ---------------------------------------------------------------- partial degree hist + per-edge rank (dense writes)
// grid: (NCHUNK, 2, 6)  z = g*2+side (side 0=src,1=dst)
__global__ __launch_bounds__(256) void count_part_kernel(
    const int* __restrict__ s0, const int* __restrict__ d0,
    const int* __restrict__ s1, const int* __restrict__ d1,
    const int* __restrict__ s2, const int* __restrict__ d2,
    int* __restrict__ partial,   // [6][NCHUNK][NNODE]
    ushort* __restrict__ rank)   // [3][NEDGE] (dst side only)
{
    __shared__ int hist[RHALF];
    int c = blockIdx.x, r = blockIdx.y, gs = blockIdx.z;
    const int* arr = (gs == 0) ? s0 : (gs == 1) ? d0 : (gs == 2) ? s1
                   : (gs == 3) ? d1 : (gs == 4) ? s2 : d2;
    for (int i = threadIdx.x; i < RHALF; i += 256) hist[i] = 0;
    __syncthreads();
    int base = r * RHALF;
    const int* p = arr + c * CHSZ;
    if (gs & 1) {
        ushort* rk = rank + (size_t)(gs >> 1) * NEDGE + c * CHSZ;
        for (int i = threadIdx.x; i < CHSZ; i += 256) {
            int v = p[i] - base;
            if ((unsigned)v < (unsigned)RHALF)
                rk[i] = (ushort)atomicAdd(&hist[v], 1);
        }
    } else {
        for (int i = threadIdx.x; i < CHSZ; i += 256) {
            int v = p[i] - base;
            if ((unsigned)v < (unsigned)RHALF) atomicAdd(&hist[v], 1);
        }
    }
    __syncthreads();
    int* outp = partial + ((size_t)gs * NCHUNK + c) * NNODE + base;
    for (int i = threadIdx.x; i < RHALF; i += 256) outp[i] = hist[i];
}

// ---------------------------------------------------------------- sum partials -> cnt[6][NNODE] (degrees, for norm)
__global__ __launch_bounds__(256) void sum_kernel(
    const int* __restrict__ partial, int* __restrict__ cnt)
{
    int idx = blockIdx.x * 256 + threadIdx.x;
    if (idx >= 6 * NNODE) return;
    int gs = idx / NNODE, node = idx - gs * NNODE;
    const int* pp = partial + (size_t)gs * NCHUNK * NNODE + node;
    int s = 0;
    #pragma unroll 8
    for (int c = 0; c < NCHUNK; ++c) s += pp[c * NNODE];
    cnt[idx] = s;
}

// ---------------------------------------------------------------- row_ptr scan (reads cnt dst-planes)
__global__ __launch_bounds__(256) void scan_kernel(
    const int* __restrict__ cnt, int* __restrict__ rp)
{
    int g = blockIdx.x;
    const int* c = cnt + (g * 2 + 1) * NNODE;   // dst side
    int* r = rp + g * (NNODE + 1);
    __shared__ int part[256];
    int t = threadIdx.x;
    constexpr int CH = (NNODE + 255) / 256;  // 65
    int lo = t * CH;
    int hi = lo + CH; if (hi > NNODE) hi = NNODE;
    int s = 0;
    for (int i = lo; i < hi; ++i) s += c[i];
    part[t] = s;
    __syncthreads();
    for (int off = 1; off < 256; off <<= 1) {
        int v = part[t];
        if (t >= off) v += part[t - off];
        __syncthreads();
        part[t] = v;
        __syncthreads();
    }
    int run = (t == 0) ? 0 : part[t - 1];
    for (int i = lo; i < hi; ++i) { r[i] = run; run += c[i]; }
    if (t == 255) r[NNODE] = part[255];
}

// ---------------------------------------------------------------- chunk_base[g][c][node] = rp[node] + excl-scan of dst partials over c
__global__ __launch_bounds__(256) void base_kernel(
    const int* __restrict__ partial, const int* __restrict__ rp,
    int* __restrict__ chunk_base)
{
    int idx = blockIdx.x * 256 + threadIdx.x;
    if (idx >= 3 * NNODE) return;
    int g = idx / NNODE, node = idx - g * NNODE;
    int running = rp[g * (NNODE + 1) + node];
    const int* pp = partial + (size_t)(g * 2 + 1) * NCHUNK * NNODE + node;
    int* ob = chunk_base + (size_t)g * NCHUNK * NNODE + node;
    #pragma unroll 8
    for (int c = 0; c < NCHUNK; ++c) { ob[c * NNODE] = running; running += pp[c * NNODE]; }
}

// ---------------------------------------------------------------- CSR fill: pure parallel scatter (1 thread / edge)
// Packed 4-byte edge: low 16 bits = src node (<32768), high 16 bits = bf16 weight
// (rsqrt norm * 1/HSCALE to undo the fp8 h scaling).
__global__ __launch_bounds__(256) void fill_scatter_kernel(
    const int* __restrict__ s0, const int* __restrict__ d0,
    const int* __restrict__ s1, const int* __restrict__ d1,
    const int* __restrict__ s2, const int* __restrict__ d2,
    const int* __restrict__ cnt, const int* __restrict__ chunk_base,
    const ushort* __restrict__ rank, uint* __restrict__ csr_packed)
{
    int e = blockIdx.x * 256 + threadIdx.x;
    int g = blockIdx.y;
    if (e >= NEDGE) return;
    const int* s = (g == 0) ? s0 : (g == 1) ? s1 : s2;
    const int* d = (g == 0) ? d0 : (g == 1) ? d1 : d2;
    int sv = s[e], dv = d[e];
    int c = e / CHSZ;
    int pos = chunk_base[((size_t)g * NCHUNK + c) * NNODE + dv]
            + (int)rank[(size_t)g * NEDGE + e];
    int a = cnt[(g * 2 + 0) * NNODE + sv]; if (a < 1) a = 1;
    int b = cnt[(g * 2 + 1) * NNODE + dv]; if (b < 1) b = 1;
    float w = rsqrtf((float)a * (float)b) * HINV;
    csr_packed[(size_t)g * NEDGE + pos] = (uint)sv | ((uint)f2bf(w) << 16);
}

// ---------------------------------------------------------------- CSR gather (fp8 h, 4B packed edges), 3-stage pipeline:
// grid (NNODE/16, 3): wave = 4 rows, 16 lanes/row, lane owns one uint2 (8 fp8 cols).
// Pipeline: descs batch k+2 || rows batch k+1 || accumulate batch k.
__global__ __launch_bounds__(256) void gather_kernel(
    const ushort* __restrict__ h8, const uint* __restrict__ csr_packed,
    const int* __restrict__ rp, ushort* __restrict__ agg)
{
    int t = threadIdx.x;
    int wave = t >> 6, lane = t & 63;
    int sub = lane >> 4, li = lane & 15;
    int g = blockIdx.y;
    int row = blockIdx.x * 16 + wave * 4 + sub;
    int js = rp[g * (NNODE + 1) + row];
    int je = rp[g * (NNODE + 1) + row + 1];
    const uint* ep = csr_packed + (size_t)g * NEDGE;
    const uint2* hb2 = (const uint2*)h8;    // one row = 128 fp8 = 16 uint2
    float ax[8];
    #pragma unroll
    for (int i = 0; i < 8; ++i) ax[i] = 0.f;
    int j = js;
    if (je - js >= 8) {
        uint a0 = ep[j], a1 = ep[j + 1], a2 = ep[j + 2], a3 = ep[j + 3];
        uint b0 = ep[j + 4], b1 = ep[j + 5], b2 = ep[j + 6], b3 = ep[j + 7];
        uint2 ra0 = hb2[(size_t)(a0 & 0x7FFFu) * 16 + li];
        uint2 ra1 = hb2[(size_t)(a1 & 0x7FFFu) * 16 + li];
        uint2 ra2 = hb2[(size_t)(a2 & 0x7FFFu) * 16 + li];
        uint2 ra3 = hb2[(size_t)(a3 & 0x7FFFu) * 16 + li];
        j += 8;
        while (j + 3 < je) {
            uint c0 = ep[j], c1 = ep[j + 1], c2 = ep[j + 2], c3 = ep[j + 3];
            uint2 rb0 = hb2[(size_t)(b0 & 0x7FFFu) * 16 + li];
            uint2 rb1 = hb2[(size_t)(b1 & 0x7FFFu) * 16 + li];
            uint2 rb2 = hb2[(size_t)(b2 & 0x7FFFu) * 16 + li];
            uint2 rb3 = hb2[(size_t)(b3 & 0x7FFFu) * 16 + li];
            accum8f8(ax, ra0, (int)(a0 & 0xFFFF0000u));
            accum8f8(ax, ra1, (int)(a1 & 0xFFFF0000u));
            accum8f8(ax, ra2, (int)(a2 & 0xFFFF0000u));
            accum8f8(ax, ra3, (int)(a3 & 0xFFFF0000u));
            a0 = b0; a1 = b1; a2 = b2; a3 = b3;
            b0 = c0; b1 = c1; b2 = c2; b3 = c3;
            ra0 = rb0; ra1 = rb1; ra2 = rb2; ra3 = rb3;
            j += 4;
        }
        // drain: A has rows; B needs rows
        uint2 rb0 = hb2[(size_t)(b0 & 0x7FFFu) * 16 + li];
        uint2 rb1 = hb2[(size_t)(b1 & 0x7FFFu) * 16 + li];
        uint2 rb2 = hb2[(size_t)(b2 & 0x7FFFu) * 16 + li];
        uint2 rb3 = hb2[(size_t)(b3 & 0x7FFFu) * 16 + li];
        accum8f8(ax, ra0, (int)(a0 & 0xFFFF0000u));
        accum8f8(ax, ra1, (int)(a1 & 0xFFFF0000u));
        accum8f8(ax, ra2, (int)(a2 & 0xFFFF0000u));
        accum8f8(ax, ra3, (int)(a3 & 0xFFFF0000u));
        accum8f8(ax, rb0, (int)(b0 & 0xFFFF0000u));
        accum8f8(ax, rb1, (int)(b1 & 0xFFFF0000u));
        accum8f8(ax, rb2, (int)(b2 & 0xFFFF0000u));
        accum8f8(ax, rb3, (int)(b3 & 0xFFFF0000u));
    }
    for (; j < je; ++j) {
        uint e0 = ep[j];
        uint2 p0 = hb2[(size_t)(e0 & 0x7FFFu) * 16 + li];
        accum8f8(ax, p0, (int)(e0 & 0xFFFF0000u));
    }
    uint4 o;
    o.x = (uint)f2bf(ax[0]) | ((uint)f2bf(ax[1]) << 16);
    o.y = (uint)f2bf(ax[2]) | ((uint)f2bf(ax[3]) << 16);
    o.z = (uint)f2bf(ax[4]) | ((uint)f2bf(ax[5]) << 16);
    o.w = (uint)f2bf(ax[6]) | ((uint)f2bf(ax[7]) << 16);
    ((uint4*)agg)[((size_t)g * NNODE + row) * 16 + li] = o;
}

// ---------------------------------------------------------------- MFMA GEMM: h_next = sum_g agg_g @ W[g,l] + bsum
// epilogue: h8 = fp8(v*HSCALE) ; layer 2: disc_acc = v ; layer 3: disc8 = fp8((disc_acc+v)*0.5*HSCALE)
__global__ __launch_bounds__(256) void gemm_kernel(
    const ushort* __restrict__ agg, const ushort* __restrict__ Wt,
    const float* __restrict__ gcnB, int layer,
    ushort* __restrict__ h8, float* __restrict__ full_acc,
    float* __restrict__ disc_acc, ushort* __restrict__ disc8)
{
    __shared__ ushort Wlds[128 * 136];   // pad 136: 2-way max bank aliasing (free)
    __shared__ float bsum[128];
    int t = threadIdx.x;
    int wave = t >> 6, lane = t & 63;
    int R0 = blockIdx.x * 64;
    if (t < 128)
        bsum[t] = gcnB[(0 * 4 + layer) * 128 + t] + gcnB[(1 * 4 + layer) * 128 + t]
                + gcnB[(2 * 4 + layer) * 128 + t];
    int m = lane & 15, q = lane >> 4;
    int arow = R0 + wave * 16 + m;
    f32x4 acc[8];
    #pragma unroll
    for (int n = 0; n < 8; ++n) acc[n] = (f32x4){0.f, 0.f, 0.f, 0.f};
    for (int g = 0; g < 3; ++g) {
        __syncthreads();
        const ushort* src = Wt + ((size_t)(g * 4 + layer) << 14);
        for (int i = t; i < 2048; i += 256) {          // 128 rows x 16 uint4
            int row = i >> 4, c = i & 15;
            *(uint4*)&Wlds[row * 136 + c * 8] = *(const uint4*)(src + row * 128 + c * 8);
        }
        __syncthreads();
        const ushort* ap = agg + ((size_t)g * NNODE + arow) * 128 + q * 8;
        bf16x8 af[4];
        #pragma unroll
        for (int k = 0; k < 4; ++k) af[k] = *(const bf16x8*)(ap + k * 32);
        #pragma unroll
        for (int n = 0; n < 8; ++n) {
            const ushort* bp = &Wlds[(n * 16 + m) * 136 + q * 8];
            #pragma unroll
            for (int k = 0; k < 4; ++k) {
                bf16x8 bfr = *(const bf16x8*)(bp + k * 32);
                acc[n] = __builtin_amdgcn_mfma_f32_16x16x32_bf16(af[k], bfr, acc[n], 0, 0, 0);
            }
        }
    }
    __syncthreads();
    float* stage = (float*)Wlds;       // reuse LDS (34816 B >= 32768 B)
    #pragma unroll
    for (int n = 0; n < 8; ++n) {
        #pragma unroll
        for (int r = 0; r < 4; ++r)
            stage[(wave * 16 + q * 4 + r) * 128 + n * 16 + m] = acc[n][r];
    }
    __syncthreads();
    for (int idx = t; idx < 64 * 64; idx += 256) {     // col-pair granularity
        int row = idx >> 6, cp = idx & 63;
        int gr = R0 + row;
        int c0 = cp * 2;
        float v0 = stage[row * 128 + c0] + bsum[c0];
        float v1 = stage[row * 128 + c0 + 1] + bsum[c0 + 1];
        size_t o = (size_t)gr * 128 + c0;
        float2 f = *(float2*)&full_acc[o];
        f.x += v0; f.y += v1;
        *(float2*)&full_acc[o] = f;
        h8[(size_t)gr * 64 + cp] = fp8_pk2(hclamp(v0 * HSCALE), hclamp(v1 * HSCALE));
        if (gr >= KDIM) {
            size_t od = (size_t)(gr - KDIM) * 64 + cp;
            if (layer == 2) {
                *(float2*)&disc_acc[od * 2] = make_float2(v0, v1);
            } else if (layer == 3) {
                float2 dv = *(const float2*)&disc_acc[od * 2];
                disc8[od] = fp8_pk2(hclamp((dv.x + v0) * 0.5f * HSCALE),
                                    hclamp((dv.y + v1) * 0.5f * HSCALE));
            }
        }
    }
}

// ---------------------------------------------------------------- fused pool + head: 16 batch rows per block
// pooling reads fp8 disc rows (128 B/row); 1/HSCALE folded into the mean divide.
__global__ __launch_bounds__(256) void pool_head_kernel(
    const ushort* __restrict__ disc8, const int* __restrict__ hist,
    const int* __restrict__ segids,
    const float* __restrict__ full,
    const float* __restrict__ fsW, const float* __restrict__ fsB,
    const float* __restrict__ feW, const float* __restrict__ feB,
    const float* __restrict__ disc_emb, const int* __restrict__ exer_id,
    const float* __restrict__ kn,
    const ushort* __restrict__ W1t, const float* __restrict__ b1,
    const ushort* __restrict__ W2t, const float* __restrict__ b2,
    const float* __restrict__ W3, const float* __restrict__ b3,
    float* __restrict__ out)
{
    __shared__ ushort xsl[16][136];   // x bf16, A-layout readable
    __shared__ ushort o1l[16][520];   // o1 bf16
    __shared__ float  o2l[16][228];   // o2 f32
    __shared__ float  cwl[256];       // concept @ W[K:], scaled 0.2
    __shared__ float  sdl[16];        // pooled-stu dot fsW[:K]
    int t = threadIdx.x, wave = t >> 6, lane = t & 63;
    int b0 = blockIdx.x * 16;
    float fsb = fsB[0], feb = feB[0];
    // ---- stage A1: cw (redundant per block; 128-len dot per thread)
    {
        int j = t & 127;
        const float* w = (t < 128) ? (fsW + KDIM) : (feW + KDIM);
        const float* row = full + (size_t)j * KDIM;
        float s = 0.f;
        for (int k = 0; k < KDIM; ++k) s += row[k] * w[k];
        cwl[t] = s * 0.2f;   // fold full/5
    }
    // ---- stage A2: history pooling over fp8 rows -> sd (wave = 4 rows, 16 lanes/row)
    {
        int sub = lane >> 4, li = lane & 15;
        int rr = wave * 4 + sub;
        int b = b0 + rr;
        auto bsearch = [&](int key) {
            int lo = 0, hi = NHIST;
            while (lo < hi) {
                int m = (lo + hi) >> 1;
                if (segids[m] < key) lo = m + 1; else hi = m;
            }
            return lo;
        };
        int js = bsearch(b), je = bsearch(b + 1);
        const uint2* db2 = (const uint2*)disc8;   // one row = 128 fp8 = 16 uint2
        float ax[8];
        #pragma unroll
        for (int i = 0; i < 8; ++i) ax[i] = 0.f;
        int one = __float_as_int(1.0f);
        int j = js;
        if (je - js >= 8) {
            int a0 = hist[j], a1 = hist[j + 1], a2 = hist[j + 2], a3 = hist[j + 3];
            int b0i = hist[j + 4], b1i = hist[j + 5], b2i = hist[j + 6], b3i = hist[j + 7];
            uint2 ra0 = db2[(size_t)a0 * 16 + li];
            uint2 ra1 = db2[(size_t)a1 * 16 + li];
            uint2 ra2 = db2[(size_t)a2 * 16 + li];
            uint2 ra3 = db2[(size_t)a3 * 16 + li];
            j += 8;
            while (j + 3 < je) {
                int c0 = hist[j], c1 = hist[j + 1], c2 = hist[j + 2], c3 = hist[j + 3];
                uint2 rb0 = db2[(size_t)b0i * 16 + li];
                uint2 rb1 = db2[(size_t)b1i * 16 + li];
                uint2 rb2 = db2[(size_t)b2i * 16 + li];
                uint2 rb3 = db2[(size_t)b3i * 16 + li];
                accum8f8(ax, ra0, one); accum8f8(ax, ra1, one);
                accum8f8(ax, ra2, one); accum8f8(ax, ra3, one);
                b0i = c0; b1i = c1; b2i = c2; b3i = c3;
                ra0 = rb0; ra1 = rb1; ra2 = rb2; ra3 = rb3;
                j += 4;
            }
            uint2 rb0 = db2[(size_t)b0i * 16 + li];
            uint2 rb1 = db2[(size_t)b1i * 16 + li];
            uint2 rb2 = db2[(size_t)b2i * 16 + li];
            uint2 rb3 = db2[(size_t)b3i * 16 + li];
            accum8f8(ax, ra0, one); accum8f8(ax, ra1, one);
            accum8f8(ax, ra2, one); accum8f8(ax, ra3, one);
            accum8f8(ax, rb0, one); accum8f8(ax, rb1, one);
            accum8f8(ax, rb2, one); accum8f8(ax, rb3, one);
        }
        for (; j < je; ++j) {
            uint2 p = db2[(size_t)hist[j] * 16 + li];
            accum8f8(ax, p, one);
        }
        float c = (float)(je - js); if (c < 1.f) c = 1.f;
        float inv = HINV / c;            // mean divide + undo fp8 scale
        float sd = 0.f;
        #pragma unroll
        for (int k = 0; k < 8; ++k) sd += ax[k] * inv * fsW[li * 8 + k];
        #pragma unroll
        for (int o = 8; o > 0; o >>= 1) sd += __shfl_xor(sd, o, 16);
        if (li == 0) sdl[rr] = sd;
    }
    __syncthreads();
    // ---- stage B: build x rows (bf16)
    #pragma unroll
    for (int i = 0; i < 4; ++i) {
        int rr = wave * 4 + i;
        int b = b0 + rr;
        int eid = exer_id[b];
        const float* er = full + (size_t)(KDIM + eid) * KDIM;
        float ed = er[lane] * feW[lane] + er[lane + 64] * feW[lane + 64];
        #pragma unroll
        for (int o = 32; o > 0; o >>= 1) ed += __shfl_xor(ed, o);
        ed *= 0.2f;   // fold full/5
        float sd = sdl[rr];
        float edisc = 10.f * sigmoidf(disc_emb[eid]);
        for (int j = lane; j < KDIM; j += 64) {
            float prof = sigmoidf(sd + cwl[j] + fsb);
            float diff = sigmoidf(ed + cwl[KDIM + j] + feb);
            xsl[rr][j] = f2bf(edisc * (prof - diff) * kn[(size_t)b * KDIM + j]);
        }
    }
    __syncthreads();
    int m = lane & 15, q = lane >> 4;
    // ---- layer 1 MFMA: wave handles n in [wave*128, wave*128+128)
    bf16x8 af[4];
    #pragma unroll
    for (int kk = 0; kk < 4; ++kk) af[kk] = *(const bf16x8*)&xsl[m][kk * 32 + q * 8];
    f32x4 acc[8];
    #pragma unroll
    for (int n = 0; n < 8; ++n) acc[n] = (f32x4){0.f, 0.f, 0.f, 0.f};
    const ushort* w1base = W1t + (size_t)(wave * 128) * 128;
    #pragma unroll
    for (int nt = 0; nt < 8; ++nt) {
        const ushort* bp = w1base + (nt * 16 + m) * 128 + q * 8;
        #pragma unroll
        for (int kk = 0; kk < 4; ++kk) {
            bf16x8 bf = *(const bf16x8*)(bp + kk * 32);
            acc[nt] = __builtin_amdgcn_mfma_f32_16x16x32_bf16(af[kk], bf, acc[nt], 0, 0, 0);
        }
    }
    #pragma unroll
    for (int nt = 0; nt < 8; ++nt) {
        int n = wave * 128 + nt * 16 + m;
        float bv = b1[n];
        #pragma unroll
        for (int r = 0; r < 4; ++r)
            o1l[q * 4 + r][n] = f2bf(sigmoidf(acc[nt][r] + bv));
    }
    __syncthreads();
    // ---- layer 2 MFMA: 14 n-tiles distributed: wave w takes nt = w, w+4, w+8, (w+12)
    int ntt = (wave < 2) ? 4 : 3;
    f32x4 acc2[4];
    #pragma unroll
    for (int i = 0; i < 4; ++i) acc2[i] = (f32x4){0.f, 0.f, 0.f, 0.f};
    #pragma unroll 4
    for (int kk = 0; kk < 16; ++kk) {
        bf16x8 a2 = *(const bf16x8*)&o1l[m][kk * 32 + q * 8];
        #pragma unroll
        for (int tt = 0; tt < 4; ++tt) {
            if (tt < ntt) {
                int nt = wave + 4 * tt;
                bf16x8 bf = *(const bf16x8*)(W2t + (size_t)(nt * 16 + m) * 512 + kk * 32 + q * 8);
                acc2[tt] = __builtin_amdgcn_mfma_f32_16x16x32_bf16(a2, bf, acc2[tt], 0, 0, 0);
            }
        }
    }
    #pragma unroll
    for (int tt = 0; tt < 4; ++tt) {
        if (tt < ntt) {
            int nt = wave + 4 * tt;
            int n = nt * 16 + m;
            if (n < 216) {
                float bv = b2[n];
                #pragma unroll
                for (int r = 0; r < 4; ++r)
                    o2l[q * 4 + r][n] = sigmoidf(acc2[tt][r] + bv);
            }
        }
    }
    __syncthreads();
    // ---- layer 3: 16-lane dot per row
    int sub = lane >> 4, li = lane & 15;
    int rr = wave * 4 + sub;
    float dot = 0.f;
    for (int p = li; p < 216; p += 16) dot += o2l[rr][p] * W3[p];
    #pragma unroll
    for (int o = 8; o > 0; o >>= 1) dot += __shfl_xor(dot, o, 16);
    if (li == 0) out[b0 + rr] = sigmoidf(dot + b3[0]);
}

// ================================================================ host
extern "C" void kernel_launch(void* const* d_in, const int* in_sizes, int n_in,
                              void* d_out, int out_size, void* d_ws, size_t ws_size,
                              hipStream_t stream)
{
    (void)in_sizes; (void)n_in; (void)out_size; (void)ws_size;
    const float* entity = (const float*)d_in[0];
    const float* gcnW   = (const float*)d_in[1];
    const float* gcnB   = (const float*)d_in[2];
    const float* fsW    = (const float*)d_in[3];
    const float* fsB    = (const float*)d_in[4];
    const float* feW    = (const float*)d_in[5];
    const float* feB    = (const float*)d_in[6];
    const float* disc_emb = (const float*)d_in[7];
    const float* W1 = (const float*)d_in[8];
    const float* b1 = (const float*)d_in[9];
    const float* W2 = (const float*)d_in[10];
    const float* b2 = (const float*)d_in[11];
    const float* W3 = (const float*)d_in[12];
    const float* b3 = (const float*)d_in[13];
    const int* s0 = (const int*)d_in[14];
    const int* d0 = (const int*)d_in[15];
    const int* s1 = (const int*)d_in[16];
    const int* d1 = (const int*)d_in[17];
    const int* s2 = (const int*)d_in[18];
    const int* d2 = (const int*)d_in[19];
    const int* exer_id = (const int*)d_in[21];
    const float* kn = (const float*)d_in[22];
    const int* hist = (const int*)d_in[23];
    const int* segid = (const int*)d_in[24];
    float* out = (float*)d_out;

    char* wsb = (char*)d_ws;
    size_t off = 0;
    auto alloc = [&](size_t bytes) -> void* {
        void* p = wsb + off;
        off = (off + bytes + 255) & ~(size_t)255;
        return p;
    };
    int*    partial   = (int*)alloc((size_t)6 * NCHUNK * NNODE * sizeof(int));   // 12.7 MB
    int*    cnt       = (int*)alloc((size_t)6 * NNODE * sizeof(int));
    int*    rp        = (int*)alloc((size_t)3 * (NNODE + 1) * sizeof(int));
    int*    chunk_base= (int*)alloc((size_t)3 * NCHUNK * NNODE * sizeof(int));   // 6.3 MB
    ushort* rank      = (ushort*)alloc((size_t)3 * NEDGE * sizeof(ushort));      // 2.4 MB
    uint*   csr_packed= (uint*)alloc((size_t)3 * NEDGE * sizeof(uint));          // 4.8 MB
    ushort* h8        = (ushort*)alloc((size_t)NNODE * KDIM);                    // fp8: 2.1 MB
    ushort* agg       = (ushort*)alloc((size_t)3 * NNODE * KDIM * sizeof(ushort));
    ushort* Wt        = (ushort*)alloc((size_t)3 * 4 * KDIM * KDIM * sizeof(ushort));
    ushort* W1t       = (ushort*)alloc((size_t)512 * 128 * sizeof(ushort));
    ushort* W2t       = (ushort*)alloc((size_t)224 * 512 * sizeof(ushort));
    float*  full_acc  = (float*)alloc((size_t)NNODE * KDIM * sizeof(float));
    float*  disc_acc  = (float*)alloc((size_t)NEXER * KDIM * sizeof(float));
    ushort* disc8     = (ushort*)alloc((size_t)NEXER * KDIM);                    // fp8: 2.1 MB

    prep_all_kernel<<<EMB_BLOCKS + W_BLOCKS + HEAD_BLOCKS, 256, 0, stream>>>(
        entity, h8, full_acc, gcnW, Wt, W1, W2, W1t, W2t);

    // CSR build: LDS-hist counting (ranks recorded), then fully parallel scatter
    count_part_kernel<<<dim3(NCHUNK, 2, 6), 256, 0, stream>>>(s0, d0, s1, d1, s2, d2,
                                                              partial, rank);
    sum_kernel<<<(6 * NNODE + 255) / 256, 256, 0, stream>>>(partial, cnt);
    scan_kernel<<<3, 256, 0, stream>>>(cnt, rp);
    base_kernel<<<(3 * NNODE + 255) / 256, 256, 0, stream>>>(partial, rp, chunk_base);
    fill_scatter_kernel<<<dim3((NEDGE + 255) / 256, 3), 256, 0, stream>>>(
        s0, d0, s1, d1, s2, d2, cnt, chunk_base, rank, csr_packed);

    for (int l = 0; l < 4; ++l) {
        gather_kernel<<<dim3(NNODE / 16, 3), 256, 0, stream>>>(h8, csr_packed, rp, agg);
        gemm_kernel<<<NNODE / 64, 256, 0, stream>>>(agg, Wt, gcnB, l, h8, full_acc,
                                                    disc_acc, disc8);
    }

    pool_head_kernel<<<NBATCH / 16, 256, 0, stream>>>(disc8, hist, segid,
                                                      full_acc, fsW, fsB, feW, feB,
                                                      disc_emb, exer_id, kn,
                                                      W1t, b1, W2t, b2, W3, b3, out);
}